// Round 4
// baseline (786.334 us; speedup 1.0000x reference)
//
#include <hip/hip_runtime.h>
#include <hip/hip_bf16.h>
#include <math.h>

#define N_NODES 50000
#define N_EDGES 250000
#define BB      128
#define DD      302
#define QQ      600
#define CC      2000
#define NEG_SLOPE 0.2f
#define GS      304        // padded row stride for G and P (16B-aligned rows)
#define KP      320        // padded K (10 x 32)
#define KSTEPS  10         // KP / 32
#define PC      64         // nodes per pooling chunk
#define BPK_KS  20480      // shorts per k-step in packed B: [hi 320x32][lo 320x32]

typedef __attribute__((ext_vector_type(8))) short short8;
typedef __attribute__((ext_vector_type(4))) float f32x4;

__device__ __forceinline__ void gload_lds16(const void* g, void* l) {
    __builtin_amdgcn_global_load_lds((const __attribute__((address_space(1))) void*)g,
                                     (__attribute__((address_space(3))) void*)l, 16, 0, 0);
}

// ---------------------------------------------------------------- CSR build
__global__ void k_deg_init(int* deg, int* cursor) {
    int i = blockIdx.x * blockDim.x + threadIdx.x;
    if (i < N_NODES) { deg[i] = 1; cursor[i] = 0; }  // 1 = self loop
}

__global__ void k_histogram(const int* __restrict__ dst, int* deg) {
    int e = blockIdx.x * blockDim.x + threadIdx.x;
    if (e < N_EDGES) atomicAdd(&deg[dst[e]], 1);
}

__global__ void k_scan_block(const int* __restrict__ deg, int* offs, int* partials) {
    __shared__ int sh[256];
    int i = blockIdx.x * 256 + threadIdx.x;
    int v = (i < N_NODES) ? deg[i] : 0;
    sh[threadIdx.x] = v;
    __syncthreads();
    for (int d = 1; d < 256; d <<= 1) {
        int t = (threadIdx.x >= d) ? sh[threadIdx.x - d] : 0;
        __syncthreads();
        sh[threadIdx.x] += t;
        __syncthreads();
    }
    if (i < N_NODES) offs[i] = sh[threadIdx.x] - v;   // exclusive
    if (threadIdx.x == 255) partials[blockIdx.x] = sh[255];
}

__global__ void k_scan_partials(int* partials, int nb) {
    __shared__ int sh[256];
    int v = (threadIdx.x < nb) ? partials[threadIdx.x] : 0;
    sh[threadIdx.x] = v;
    __syncthreads();
    for (int d = 1; d < 256; d <<= 1) {
        int t = (threadIdx.x >= d) ? sh[threadIdx.x - d] : 0;
        __syncthreads();
        sh[threadIdx.x] += t;
        __syncthreads();
    }
    if (threadIdx.x < nb) partials[threadIdx.x] = sh[threadIdx.x] - v;  // exclusive
}

__global__ void k_scan_add(int* offs, const int* __restrict__ partials) {
    int i = blockIdx.x * 256 + threadIdx.x;
    if (i < N_NODES) offs[i] += partials[blockIdx.x];
}

__global__ void k_scatter(const int* __restrict__ src, const int* __restrict__ dst,
                          const int* __restrict__ offs, int* cursor, int* esrc) {
    int i = blockIdx.x * blockDim.x + threadIdx.x;
    if (i < N_EDGES) {
        int d = dst[i];
        int pos = offs[d] + atomicAdd(&cursor[d], 1);
        esrc[pos] = src[i];
    } else if (i < N_EDGES + N_NODES) {
        int n = i - N_EDGES;
        int pos = offs[n] + atomicAdd(&cursor[n], 1);
        esrc[pos] = n;   // self loop
    }
}

// ---------------------------------------------------------------- theta -> k-major packed hi/lo bf16
// bpk layout: for each k-step ks: [hi: 320 rows x 32 k][lo: 320 rows x 32 k], contiguous 40KB.
__global__ void k_theta_prep(const float* __restrict__ theta,
                             unsigned short* __restrict__ bpk) {
    int idx = blockIdx.x * 256 + threadIdx.x;
    if (idx >= KP * KP) return;
    int n = idx / KP, k = idx % KP;
    float v = (n < DD && k < DD) ? theta[n * DD + k] : 0.f;
    unsigned int u  = __float_as_uint(v);
    unsigned int uh = (u + 0x8000u) & 0xffff0000u;    // round-half-up bf16
    float hf = __uint_as_float(uh);
    float lo = v - hf;
    unsigned int ul = (__float_as_uint(lo) + 0x8000u) >> 16;
    int ks = k >> 5, kk = k & 31;
    size_t base = (size_t)ks * BPK_KS + n * 32 + kk;
    bpk[base]         = (unsigned short)(uh >> 16);
    bpk[base + 10240] = (unsigned short)ul;
}

// v_s = theta^T @ att_src, v_d = theta^T @ att_dst; packed as B rows DD, DD+1.
__global__ void k_attvec(const float* __restrict__ theta,
                         const float* __restrict__ att_src,
                         const float* __restrict__ att_dst,
                         unsigned short* __restrict__ bpk) {
    int k = blockIdx.x * 256 + threadIdx.x;
    if (k >= DD) return;
    float vs = 0.f, vd = 0.f;
    for (int j = 0; j < DD; j++) {
        float t = theta[j * DD + k];      // coalesced over k
        vs += t * att_src[j];
        vd += t * att_dst[j];
    }
    int ks = k >> 5, kk = k & 31;
    size_t b0 = (size_t)ks * BPK_KS + DD * 32 + kk;
    size_t b1 = (size_t)ks * BPK_KS + (DD + 1) * 32 + kk;
    unsigned int u, uh, ul;
    u  = __float_as_uint(vs);
    uh = (u + 0x8000u) & 0xffff0000u;
    ul = (__float_as_uint(vs - __uint_as_float(uh)) + 0x8000u) >> 16;
    bpk[b0]         = (unsigned short)(uh >> 16);
    bpk[b0 + 10240] = (unsigned short)ul;
    u  = __float_as_uint(vd);
    uh = (u + 0x8000u) & 0xffff0000u;
    ul = (__float_as_uint(vd - __uint_as_float(uh)) + 0x8000u) >> 16;
    bpk[b1]         = (unsigned short)(uh >> 16);
    bpk[b1 + 10240] = (unsigned short)ul;
}

// ---------------------------------------------------------------- split-bf16 MFMA GEMM
// 128-row tile, 512 threads / 8 waves (2 row-groups x 4 col-groups).
// B: staged per k-step via global_load_lds dwordx4 (wave-uniform LDS base +
//    lane*16; linear packed source) -- no VGPR round-trip, no ds_write.
// A: per-lane fragment rows loaded directly fp32 from global (L1-served 4x
//    reuse across the col-group waves), converted to hi/lo bf16 in regs.
// LDS = 40KB (B only) -> up to 4 blocks/CU co-resident.
__global__ __launch_bounds__(512) void k_mfma_gemm(const float* __restrict__ A, int lda,
                                                   const unsigned short* __restrict__ Bpk,
                                                   float* __restrict__ C,
                                                   float* __restrict__ a_s,
                                                   float* __restrict__ a_d, int M) {
    __shared__ __attribute__((aligned(16))) unsigned short Bs[BPK_KS]; // 40KB

    const int tid   = threadIdx.x;
    const int lane  = tid & 63;
    const int wave  = tid >> 6;         // 0..7
    const int wr    = wave >> 2;        // 0..1  (row group, 64 rows)
    const int wc    = wave & 3;         // 0..3  (col group, 80 cols)
    const int q     = lane >> 4;        // 0..3
    const int mr    = lane & 15;
    const int m0    = blockIdx.x * 128 + wr * 64;
    const int nbase = wc * 80;
    const int kvalid = (lda == GS) ? GS : DD;   // readable floats per A row

    f32x4 acc[4][5];
    #pragma unroll
    for (int i = 0; i < 4; i++)
        #pragma unroll
        for (int j = 0; j < 5; j++)
            acc[i][j] = (f32x4){0.f, 0.f, 0.f, 0.f};

    // per-lane A row pointers (lane mr owns row mt*16+mr; q selects the k-chunk)
    const float* arow[4];
    bool rok[4];
    #pragma unroll
    for (int mt = 0; mt < 4; mt++) {
        int row = m0 + mt * 16 + mr;
        rok[mt]  = row < M;
        arow[mt] = A + (size_t)(row < M ? row : 0) * lda;
    }

    const char* gB = (const char*)Bpk;

    for (int ks = 0; ks < KSTEPS; ks++) {
        const int gk0 = ks * 32;
        const int k0c = gk0 + q * 8;

        // ---- issue A fragment loads (fp32, per-lane rows)
        float f[4][8];
        #pragma unroll
        for (int mt = 0; mt < 4; mt++) {
            if (rok[mt] && (k0c + 8 <= kvalid)) {
                float4 v0 = *(const float4*)(arow[mt] + k0c);
                float4 v1 = *(const float4*)(arow[mt] + k0c + 4);
                f[mt][0]=v0.x; f[mt][1]=v0.y; f[mt][2]=v0.z; f[mt][3]=v0.w;
                f[mt][4]=v1.x; f[mt][5]=v1.y; f[mt][6]=v1.z; f[mt][7]=v1.w;
            } else {
                #pragma unroll
                for (int p = 0; p < 8; p += 2) {
                    int k = k0c + p;
                    float2 t = {0.f, 0.f};
                    if (rok[mt] && k < kvalid) t = *(const float2*)(arow[mt] + k);  // DD even
                    f[mt][p] = t.x; f[mt][p+1] = t.y;
                }
            }
        }

        // ---- stage B k-slice via global_load_lds (40KB, linear)
        {
            const char* gsrc = gB + (size_t)(ks * BPK_KS) * 2;
            #pragma unroll
            for (int j = 0; j < 5; j++) {
                int chunk = j * 8 + wave;                 // 0..39, wave-uniform
                gload_lds16(gsrc + chunk * 1024 + lane * 16,
                            (char*)Bs + chunk * 1024);
            }
        }

        __syncthreads();    // B in LDS; A loads also landed (vmcnt drain)

        // ---- convert A to hi/lo bf16 in regs
        short8 ah[4], al[4];
        #pragma unroll
        for (int mt = 0; mt < 4; mt++) {
            #pragma unroll
            for (int p = 0; p < 8; p++) {
                unsigned int u  = __float_as_uint(f[mt][p]);
                unsigned int uh = (u + 0x8000u) & 0xffff0000u;   // round-half-up bf16
                float l = f[mt][p] - __uint_as_float(uh);
                ah[mt][p] = (short)(uh >> 16);
                al[mt][p] = (short)((__float_as_uint(l) + 0x8000u) >> 16);
            }
        }

        // ---- B fragments from LDS + 3-pass split MFMA
        short8 bh[5], bl[5];
        #pragma unroll
        for (int nt = 0; nt < 5; nt++) {
            int off = (nbase + nt * 16 + mr) * 32 + q * 8;
            bh[nt] = *(const short8*)&Bs[off];
            bl[nt] = *(const short8*)&Bs[10240 + off];
        }
        #pragma unroll
        for (int nt = 0; nt < 5; nt++) {
            #pragma unroll
            for (int mt = 0; mt < 4; mt++) {
                acc[mt][nt] = __builtin_amdgcn_mfma_f32_16x16x32_bf16(ah[mt], bh[nt], acc[mt][nt], 0, 0, 0);
                acc[mt][nt] = __builtin_amdgcn_mfma_f32_16x16x32_bf16(ah[mt], bl[nt], acc[mt][nt], 0, 0, 0);
                acc[mt][nt] = __builtin_amdgcn_mfma_f32_16x16x32_bf16(al[mt], bh[nt], acc[mt][nt], 0, 0, 0);
            }
        }

        __syncthreads();    // LDS reads done before next-step overwrite
    }

    // epilogue: C/D layout col=lane&15, row=(lane>>4)*4+reg; zero C pad cols 302/303
    #pragma unroll
    for (int mt = 0; mt < 4; mt++) {
        int row_b = m0 + mt * 16 + q * 4;
        #pragma unroll
        for (int nt = 0; nt < 5; nt++) {
            int col = nbase + nt * 16 + mr;
            if (col > DD + 1) continue;
            #pragma unroll
            for (int r = 0; r < 4; r++) {
                int row = row_b + r;
                if (row >= M) continue;
                float v = acc[mt][nt][r];
                if (col < DD) {
                    C[(size_t)row * GS + col] = v;
                } else if (col == DD) {
                    a_s[row] = v;
                    C[(size_t)row * GS + DD] = 0.f;       // keep pad col zero
                } else {
                    a_d[row] = v;
                    C[(size_t)row * GS + DD + 1] = 0.f;   // keep pad col zero
                }
            }
        }
    }
}

// ---------------------------------------------------------------- tiled SGEMM (final linear)
#define BM 64
#define BN 64
#define BK 16
__global__ __launch_bounds__(256) void k_gemm_nt(const float* __restrict__ A,
                                                 const float* __restrict__ B,
                                                 float* __restrict__ C,
                                                 int M, int N, int K,
                                                 const float* __restrict__ bias) {
    __shared__ float As[BK][BM + 4];
    __shared__ float Bs[BK][BN + 4];
    int m0 = blockIdx.y * BM;
    int n0 = blockIdx.x * BN;
    int tid = threadIdx.x;
    int tr = tid >> 4;
    int tc = tid & 15;
    float acc[4][4] = {};
    for (int k0 = 0; k0 < K; k0 += BK) {
        #pragma unroll
        for (int j = 0; j < 4; j++) {
            int e = tid + 256 * j;
            int r = e >> 4;
            int k = e & 15;
            int gk = k0 + k;
            int gm = m0 + r;
            float va = 0.f;
            if (gm < M && gk < K) va = A[(size_t)gm * K + gk];
            As[k][r] = va;
            int gn = n0 + r;
            float vb = 0.f;
            if (gn < N && gk < K) vb = B[(size_t)gn * K + gk];
            Bs[k][r] = vb;
        }
        __syncthreads();
        #pragma unroll
        for (int k = 0; k < BK; k++) {
            float a[4], b[4];
            #pragma unroll
            for (int i = 0; i < 4; i++) a[i] = As[k][tr * 4 + i];
            #pragma unroll
            for (int j = 0; j < 4; j++) b[j] = Bs[k][tc * 4 + j];
            #pragma unroll
            for (int i = 0; i < 4; i++)
                #pragma unroll
                for (int j = 0; j < 4; j++)
                    acc[i][j] += a[i] * b[j];
        }
        __syncthreads();
    }
    #pragma unroll
    for (int i = 0; i < 4; i++) {
        int gm = m0 + tr * 4 + i;
        if (gm >= M) continue;
        #pragma unroll
        for (int j = 0; j < 4; j++) {
            int gn = n0 + tc * 4 + j;
            if (gn < N) {
                float v = acc[i][j];
                if (bias) v += bias[gn];
                C[(size_t)gm * N + gn] = v;
            }
        }
    }
}

// ---------------------------------------------------------------- qp = query @ attW  (thread/output)
__global__ __launch_bounds__(256) void k_qp(const float* __restrict__ query,
                                            const float* __restrict__ attW,
                                            float* __restrict__ qp) {
    int b = blockIdx.y;
    int d = blockIdx.x * 256 + threadIdx.x;
    if (d >= DD) return;
    const float* qrow = query + (size_t)b * QQ;
    float acc = 0.f;
    #pragma unroll 8
    for (int q = 0; q < QQ; q++) acc += qrow[q] * attW[(size_t)q * DD + d];
    qp[(size_t)b * DD + d] = acc;
}

// ---------------------------------------------------------------- softmax-aggregate (wave / dst node)
// float4 gather: rows of h have zeroed pad cols 302/303 (GEMM epilogue + this kernel's writes).
__global__ __launch_bounds__(256) void k_aggregate(const float* __restrict__ h,
                                                   const float* __restrict__ a_s,
                                                   const float* __restrict__ a_d,
                                                   const int* __restrict__ offs,
                                                   const int* __restrict__ deg,
                                                   const int* __restrict__ esrc,
                                                   const float* __restrict__ bias,
                                                   float* __restrict__ out) {
    int gid = blockIdx.x * blockDim.x + threadIdx.x;
    int n = gid >> 6, lane = gid & 63;
    if (n >= N_NODES) return;
    int beg = offs[n], cnt = deg[n];
    float adn = a_d[n];
    float m = -INFINITY;
    for (int i = lane; i < cnt; i += 64) {
        float e = a_s[esrc[beg + i]] + adn;
        e = (e > 0.f) ? e : NEG_SLOPE * e;
        m = fmaxf(m, e);
    }
    for (int off = 32; off; off >>= 1) m = fmaxf(m, __shfl_xor(m, off));
    float den = 0.f;
    for (int i = lane; i < cnt; i += 64) {
        float e = a_s[esrc[beg + i]] + adn;
        e = (e > 0.f) ? e : NEG_SLOPE * e;
        den += __expf(e - m);
    }
    for (int off = 32; off; off >>= 1) den += __shfl_xor(den, off);
    float inv_den = 1.f / den;

    const int c0 = lane * 4;            // 0..252  (covers cols 0..255)
    const int c1 = 256 + lane * 4;      // lanes 0..11 cover cols 256..303
    const bool has1 = lane < 12;
    float4 A0 = {0.f, 0.f, 0.f, 0.f};
    float4 A1 = {0.f, 0.f, 0.f, 0.f};
    for (int i = 0; i < cnt; i++) {
        int s = esrc[beg + i];
        float e = a_s[s] + adn;
        e = (e > 0.f) ? e : NEG_SLOPE * e;
        float w = __expf(e - m) * inv_den;
        const float* row = h + (size_t)s * GS;
        float4 r0 = *(const float4*)(row + c0);
        A0.x += w * r0.x; A0.y += w * r0.y; A0.z += w * r0.z; A0.w += w * r0.w;
        if (has1) {
            float4 r1 = *(const float4*)(row + c1);
            A1.x += w * r1.x; A1.y += w * r1.y; A1.z += w * r1.z; A1.w += w * r1.w;
        }
    }
    {
        float4 b0 = *(const float4*)(bias + c0);      // c0 <= 252: in-bounds
        float4 o;
        o.x = fmaxf(A0.x + b0.x, 0.f);
        o.y = fmaxf(A0.y + b0.y, 0.f);
        o.z = fmaxf(A0.z + b0.z, 0.f);
        o.w = fmaxf(A0.w + b0.w, 0.f);
        *(float4*)(out + (size_t)n * GS + c0) = o;
    }
    if (lane < 11) {                                  // cols 256..299
        float4 b1 = *(const float4*)(bias + c1);
        float4 o;
        o.x = fmaxf(A1.x + b1.x, 0.f);
        o.y = fmaxf(A1.y + b1.y, 0.f);
        o.z = fmaxf(A1.z + b1.z, 0.f);
        o.w = fmaxf(A1.w + b1.w, 0.f);
        *(float4*)(out + (size_t)n * GS + c1) = o;
    } else if (lane == 11) {                          // cols 300,301 valid; 302,303 -> 0
        float4 o;
        o.x = fmaxf(A1.x + bias[300], 0.f);
        o.y = fmaxf(A1.y + bias[301], 0.f);
        o.z = 0.f;
        o.w = 0.f;
        *(float4*)(out + (size_t)n * GS + 300) = o;
    }
}

// ---------------------------------------------------------------- pooling pieces
// batch is SORTED -> per-graph bounds via binary search (no atomics).
__global__ void k_gbounds(const int* __restrict__ batch, int* goffs, int* gcnt) {
    __shared__ int bound[BB + 1];
    int b = threadIdx.x;
    if (b <= BB) {
        int lo = 0, hi = N_NODES;
        while (lo < hi) {                 // first i with batch[i] >= b
            int mid = (lo + hi) >> 1;
            if (batch[mid] < b) lo = mid + 1; else hi = mid;
        }
        bound[b] = lo;
    }
    __syncthreads();
    if (b < BB) {
        goffs[b] = bound[b];
        gcnt[b]  = bound[b + 1] - bound[b];
    }
}

__global__ void k_scores(const float* __restrict__ h, int ld,
                         const float* __restrict__ qp,
                         const int* __restrict__ batch, float* sarr) {
    int gid = blockIdx.x * blockDim.x + threadIdx.x;
    int n = gid >> 6, lane = gid & 63;
    if (n >= N_NODES) return;
    const float* row = h + (size_t)n * ld;
    const float* q = qp + (size_t)batch[n] * DD;
    float acc = 0.f;
    for (int j = lane; j < DD; j += 64) acc += row[j] * q[j];
    for (int off = 32; off; off >>= 1) acc += __shfl_down(acc, off);
    if (lane == 0) sarr[n] = acc * 0.04082482904638630f;   // 1/sqrt(600)
}

// per-graph softmax stats over sarr
__global__ __launch_bounds__(256) void k_gstats(const float* __restrict__ sarr,
                                                const int* __restrict__ goffs,
                                                const int* __restrict__ gcnt,
                                                float* __restrict__ gm,
                                                float* __restrict__ gdeninv) {
    int b = blockIdx.x;
    int beg = goffs[b], cnt = gcnt[b];
    __shared__ float red[256];
    float m = -INFINITY;
    for (int i = threadIdx.x; i < cnt; i += 256) m = fmaxf(m, sarr[beg + i]);
    red[threadIdx.x] = m;
    __syncthreads();
    for (int d = 128; d; d >>= 1) {
        if (threadIdx.x < d) red[threadIdx.x] = fmaxf(red[threadIdx.x], red[threadIdx.x + d]);
        __syncthreads();
    }
    m = red[0];
    __syncthreads();
    float den = 0.f;
    for (int i = threadIdx.x; i < cnt; i += 256) den += __expf(sarr[beg + i] - m);
    red[threadIdx.x] = den;
    __syncthreads();
    for (int d = 128; d; d >>= 1) {
        if (threadIdx.x < d) red[threadIdx.x] += red[threadIdx.x + d];
        __syncthreads();
    }
    if (threadIdx.x == 0) {
        gm[b] = m;
        gdeninv[b] = (cnt > 0) ? 1.f / red[0] : 0.f;
    }
}

__global__ void k_wn(const float* __restrict__ sarr, const int* __restrict__ batch,
                     const float* __restrict__ gm, const float* __restrict__ gdeninv,
                     float* __restrict__ wn) {
    int n = blockIdx.x * 256 + threadIdx.x;
    if (n >= N_NODES) return;
    int b = batch[n];
    wn[n] = __expf(sarr[n] - gm[b]) * gdeninv[b];
}

__global__ void k_pzero(float* pooled) {
    int i = blockIdx.x * 256 + threadIdx.x;
    if (i < BB * DD) pooled[i] = 0.f;
}

// node-chunk-parallel weighted segment sum (batch sorted; flush at graph boundaries)
__global__ __launch_bounds__(256) void k_poolacc(const float* __restrict__ h, int ld,
                                                 const float* __restrict__ wn,
                                                 const int* __restrict__ batch,
                                                 float* __restrict__ pooled) {
    int c0 = blockIdx.x * PC;
    if (c0 >= N_NODES) return;
    int nmax = N_NODES - c0; if (nmax > PC) nmax = PC;
    __shared__ int   sb[PC];
    __shared__ float sw[PC];
    for (int i = threadIdx.x; i < nmax; i += 256) {
        sb[i] = batch[c0 + i];
        sw[i] = wn[c0 + i];
    }
    __syncthreads();
    int f0 = threadIdx.x, f1 = threadIdx.x + 256;
    float a0 = 0.f, a1 = 0.f;
    int g = sb[0];
    for (int i = 0; i < nmax; i++) {
        int bi = sb[i];
        if (bi != g) {                       // wave-uniform branch
            if (f0 < DD) atomicAdd(&pooled[(size_t)g * DD + f0], a0);
            if (f1 < DD) atomicAdd(&pooled[(size_t)g * DD + f1], a1);
            a0 = 0.f; a1 = 0.f; g = bi;
        }
        float w = sw[i];
        const float* row = h + (size_t)(c0 + i) * ld;
        if (f0 < DD) a0 += w * row[f0];
        if (f1 < DD) a1 += w * row[f1];
    }
    if (f0 < DD) atomicAdd(&pooled[(size_t)g * DD + f0], a0);
    if (f1 < DD) atomicAdd(&pooled[(size_t)g * DD + f1], a1);
}

__global__ void k_prelu(const float* __restrict__ pooled, float* __restrict__ pr) {
    int i = blockIdx.x * 256 + threadIdx.x;
    if (i < BB * DD) pr[i] = fmaxf(pooled[i], 0.f);
}

// ---------------------------------------------------------------- launch
extern "C" void kernel_launch(void* const* d_in, const int* in_sizes, int n_in,
                              void* d_out, int out_size, void* d_ws, size_t ws_size,
                              hipStream_t stream) {
    const float* x        = (const float*)d_in[0];
    const int*   edges    = (const int*)d_in[1];   // [2, E]
    const float* query    = (const float*)d_in[2];
    const int*   batch    = (const int*)d_in[3];
    const float* theta    = (const float*)d_in[4];
    const float* att_src  = (const float*)d_in[5];
    const float* att_dst  = (const float*)d_in[6];
    const float* gat_bias = (const float*)d_in[7];
    const float* attW     = (const float*)d_in[8];
    const float* lin_w    = (const float*)d_in[9];
    const float* lin_b    = (const float*)d_in[10];
    float* out = (float*)d_out;

    char* ws = (char*)d_ws;
    size_t off = 0;
    auto alloc = [&](size_t bytes) -> void* {
        off = (off + 255) & ~(size_t)255;
        void* p = ws + off;
        off += bytes;
        return p;
    };

    float* G    = (float*)alloc((size_t)N_NODES * GS * 4);   // gemm output (padded stride)
    float* P    = (float*)alloc((size_t)N_NODES * GS * 4);   // layer output (padded stride)
    unsigned short* bpk = (unsigned short*)alloc((size_t)KSTEPS * BPK_KS * 2); // packed B, 409.6KB
    float* a_s  = (float*)alloc((size_t)N_NODES * 4);
    float* a_d  = (float*)alloc((size_t)N_NODES * 4);
    float* sarr = (float*)alloc((size_t)N_NODES * 4);
    float* wn   = (float*)alloc((size_t)N_NODES * 4);
    int* deg    = (int*)alloc((size_t)N_NODES * 4);
    int* cursor = (int*)alloc((size_t)N_NODES * 4);
    int* offs   = (int*)alloc((size_t)N_NODES * 4);
    int* esrc   = (int*)alloc((size_t)(N_EDGES + N_NODES) * 4);
    int* partials = (int*)alloc(256 * 4);
    int* gcnt   = (int*)alloc(BB * 4);
    int* goffs  = (int*)alloc(BB * 4);
    float* gm   = (float*)alloc(BB * 4);
    float* gdi  = (float*)alloc(BB * 4);
    float* qp   = (float*)alloc((size_t)BB * DD * 4);
    float* pooled = (float*)alloc((size_t)BB * DD * 4);
    float* pr   = (float*)alloc((size_t)BB * DD * 4);

    const int* e_src = edges;
    const int* e_dst = edges + N_EDGES;

    const int NB_SCAN = (N_NODES + 255) / 256;   // 196

    // ---- CSR build
    k_deg_init<<<NB_SCAN, 256, 0, stream>>>(deg, cursor);
    k_histogram<<<(N_EDGES + 255) / 256, 256, 0, stream>>>(e_dst, deg);
    k_scan_block<<<NB_SCAN, 256, 0, stream>>>(deg, offs, partials);
    k_scan_partials<<<1, 256, 0, stream>>>(partials, NB_SCAN);
    k_scan_add<<<NB_SCAN, 256, 0, stream>>>(offs, partials);
    k_scatter<<<(N_EDGES + N_NODES + 255) / 256, 256, 0, stream>>>(e_src, e_dst, offs, cursor, esrc);

    // ---- theta hi/lo split (k-major packed) + attention-vector rows (once; shared across layers)
    k_theta_prep<<<(KP * KP + 255) / 256, 256, 0, stream>>>(theta, bpk);
    k_attvec<<<(DD + 255) / 256, 256, 0, stream>>>(theta, att_src, att_dst, bpk);

    // ---- 3 GAT layers
    int mfma_blocks = (N_NODES + 127) / 128;   // 391
    int wave_blocks = (N_NODES + 3) / 4;
    const float* cur = x;
    int cur_ld = DD;
    for (int layer = 0; layer < 3; layer++) {
        k_mfma_gemm<<<mfma_blocks, 512, 0, stream>>>(cur, cur_ld, bpk, G, a_s, a_d, N_NODES);
        k_aggregate<<<wave_blocks, 256, 0, stream>>>(G, a_s, a_d, offs, deg, esrc, gat_bias, P);
        cur = P;
        cur_ld = GS;
    }

    // ---- attention pooling + classifier
    {
        dim3 g((DD + 255) / 256, BB);
        k_qp<<<g, 256, 0, stream>>>(query, attW, qp);
    }
    k_gbounds<<<1, 256, 0, stream>>>(batch, goffs, gcnt);
    k_scores<<<wave_blocks, 256, 0, stream>>>(P, GS, qp, batch, sarr);
    k_gstats<<<BB, 256, 0, stream>>>(sarr, goffs, gcnt, gm, gdi);
    k_wn<<<NB_SCAN, 256, 0, stream>>>(sarr, batch, gm, gdi, wn);
    k_pzero<<<(BB * DD + 255) / 256, 256, 0, stream>>>(pooled);
    k_poolacc<<<(N_NODES + PC - 1) / PC, 256, 0, stream>>>(P, GS, wn, batch, pooled);
    k_prelu<<<(BB * DD + 255) / 256, 256, 0, stream>>>(pooled, pr);
    {
        dim3 g((CC + BN - 1) / BN, (BB + BM - 1) / BM);
        k_gemm_nt<<<g, 256, 0, stream>>>(pr, lin_w, out, BB, CC, DD, lin_b);
    }
}

// Round 6
// 732.304 us; speedup vs baseline: 1.0738x; 1.0738x over previous
//
#include <hip/hip_runtime.h>
#include <hip/hip_bf16.h>
#include <math.h>

#define N_NODES 50000
#define N_EDGES 250000
#define BB      128
#define DD      302
#define QQ      600
#define CC      2000
#define NEG_SLOPE 0.2f
#define GS      304        // padded row stride for G and P (16B-aligned rows)
#define KP      320        // padded K (10 x 32)
#define KSTEPS  10         // KP / 32
#define PC      64         // nodes per pooling chunk
#define BPK_KS  20480      // shorts per k-step in packed B: [hi 320x32][lo 320x32]

typedef __attribute__((ext_vector_type(8))) short short8;
typedef __attribute__((ext_vector_type(4))) float f32x4;

__device__ __forceinline__ void gload_lds16(const void* g, void* l) {
    __builtin_amdgcn_global_load_lds((const __attribute__((address_space(1))) void*)g,
                                     (__attribute__((address_space(3))) void*)l, 16, 0, 0);
}

// bank-spread slot for packed B: 2 lanes/bank on ds_read_b128 (free per m136)
__device__ __host__ __forceinline__ int bswz(int q, int n) {
    return q ^ (n & 3) ^ ((n >> 2) & 3);
}

// ---------------------------------------------------------------- CSR build
__global__ void k_deg_init(int* deg, int* cursor) {
    int i = blockIdx.x * blockDim.x + threadIdx.x;
    if (i < N_NODES) { deg[i] = 1; cursor[i] = 0; }  // 1 = self loop
}

__global__ void k_histogram(const int* __restrict__ dst, int* deg) {
    int e = blockIdx.x * blockDim.x + threadIdx.x;
    if (e < N_EDGES) atomicAdd(&deg[dst[e]], 1);
}

__global__ void k_scan_block(const int* __restrict__ deg, int* offs, int* partials) {
    __shared__ int sh[256];
    int i = blockIdx.x * 256 + threadIdx.x;
    int v = (i < N_NODES) ? deg[i] : 0;
    sh[threadIdx.x] = v;
    __syncthreads();
    for (int d = 1; d < 256; d <<= 1) {
        int t = (threadIdx.x >= d) ? sh[threadIdx.x - d] : 0;
        __syncthreads();
        sh[threadIdx.x] += t;
        __syncthreads();
    }
    if (i < N_NODES) offs[i] = sh[threadIdx.x] - v;   // exclusive
    if (threadIdx.x == 255) partials[blockIdx.x] = sh[255];
}

__global__ void k_scan_partials(int* partials, int nb) {
    __shared__ int sh[256];
    int v = (threadIdx.x < nb) ? partials[threadIdx.x] : 0;
    sh[threadIdx.x] = v;
    __syncthreads();
    for (int d = 1; d < 256; d <<= 1) {
        int t = (threadIdx.x >= d) ? sh[threadIdx.x - d] : 0;
        __syncthreads();
        sh[threadIdx.x] += t;
        __syncthreads();
    }
    if (threadIdx.x < nb) partials[threadIdx.x] = sh[threadIdx.x] - v;  // exclusive
}

__global__ void k_scan_add(int* offs, const int* __restrict__ partials) {
    int i = blockIdx.x * 256 + threadIdx.x;
    if (i < N_NODES) offs[i] += partials[blockIdx.x];
}

__global__ void k_scatter(const int* __restrict__ src, const int* __restrict__ dst,
                          const int* __restrict__ offs, int* cursor, int* esrc) {
    int i = blockIdx.x * blockDim.x + threadIdx.x;
    if (i < N_EDGES) {
        int d = dst[i];
        int pos = offs[d] + atomicAdd(&cursor[d], 1);
        esrc[pos] = src[i];
    } else if (i < N_EDGES + N_NODES) {
        int n = i - N_EDGES;
        int pos = offs[n] + atomicAdd(&cursor[n], 1);
        esrc[pos] = n;   // self loop
    }
}

// ---------------------------------------------------------------- theta -> k-major packed hi/lo bf16 (+attvec rows)
// bpk layout per k-step ks (40KB): [hi: 320 rows x 4 slots x 8 k][lo: same].
// Slot is bank-swizzled via bswz so GEMM ds_read_b128 is conflict-free.
// Blocks >= 400 own rows DD, DD+1 for ALL k in [0, KP) (zeros for k >= DD);
// theta blocks skip those two rows (no write race, no uninitialized entries).
__global__ void k_theta_prep(const float* __restrict__ theta,
                             const float* __restrict__ att_src,
                             const float* __restrict__ att_dst,
                             unsigned short* __restrict__ bpk) {
    if (blockIdx.x >= 400) {
        int k = (blockIdx.x - 400) * 256 + threadIdx.x;
        if (k >= KP) return;
        float vs = 0.f, vd = 0.f;
        if (k < DD) {
            for (int j = 0; j < DD; j++) {
                float t = theta[j * DD + k];      // coalesced over k
                vs += t * att_src[j];
                vd += t * att_dst[j];
            }
        }
        int ks = k >> 5, kk = k & 31, q = kk >> 3, kb = kk & 7;
        size_t b0 = (size_t)ks * BPK_KS + DD * 32 + bswz(q, DD) * 8 + kb;
        size_t b1 = (size_t)ks * BPK_KS + (DD + 1) * 32 + bswz(q, DD + 1) * 8 + kb;
        unsigned int u, uh, ul;
        u  = __float_as_uint(vs);
        uh = (u + 0x8000u) & 0xffff0000u;
        ul = (__float_as_uint(vs - __uint_as_float(uh)) + 0x8000u) >> 16;
        bpk[b0]         = (unsigned short)(uh >> 16);
        bpk[b0 + 10240] = (unsigned short)ul;
        u  = __float_as_uint(vd);
        uh = (u + 0x8000u) & 0xffff0000u;
        ul = (__float_as_uint(vd - __uint_as_float(uh)) + 0x8000u) >> 16;
        bpk[b1]         = (unsigned short)(uh >> 16);
        bpk[b1 + 10240] = (unsigned short)ul;
        return;
    }
    int idx = blockIdx.x * 256 + threadIdx.x;
    if (idx >= KP * KP) return;
    int n = idx / KP, k = idx % KP;
    if (n == DD || n == DD + 1) return;               // attvec rows owned by blocks >=400
    float v = (n < DD && k < DD) ? theta[n * DD + k] : 0.f;
    unsigned int u  = __float_as_uint(v);
    unsigned int uh = (u + 0x8000u) & 0xffff0000u;    // round-half-up bf16
    float hf = __uint_as_float(uh);
    float lo = v - hf;
    unsigned int ul = (__float_as_uint(lo) + 0x8000u) >> 16;
    int ks = k >> 5, kk = k & 31, q = kk >> 3, kb = kk & 7;
    size_t base = (size_t)ks * BPK_KS + n * 32 + bswz(q, n) * 8 + kb;
    bpk[base]         = (unsigned short)(uh >> 16);
    bpk[base + 10240] = (unsigned short)ul;
}

// ---------------------------------------------------------------- split-bf16 MFMA GEMM
// 64-row tile, 256 threads / 4 waves; EACH wave computes all 64 rows (mt<4)
// for its own 80-col group (nbase = wave*80).  Double-buffered B (2x40KB LDS)
// via global_load_lds; per k-step: issue STAGE(buf^1, ks+1) + A-prefetch(ks+1)
// FIRST, then convert+MFMA(cur), then ONE barrier (drains prefetch vmcnt,
// orders LDS reads).  Stage latency overlaps this step's compute.
__global__ __launch_bounds__(256) void k_mfma_gemm(const float* __restrict__ A, int lda,
                                                   const unsigned short* __restrict__ Bpk,
                                                   float* __restrict__ C,
                                                   float* __restrict__ a_s,
                                                   float* __restrict__ a_d, int M) {
    __shared__ __attribute__((aligned(16))) unsigned short Bs[2][BPK_KS]; // 80KB

    const int tid   = threadIdx.x;
    const int lane  = tid & 63;
    const int wave  = tid >> 6;         // 0..3
    const int q     = lane >> 4;        // 0..3
    const int mr    = lane & 15;
    const int m0    = blockIdx.x * 64;
    const int nbase = wave * 80;
    const int kvalid = (lda == GS) ? GS : DD;   // readable floats per A row

    f32x4 acc[4][5];
    #pragma unroll
    for (int i = 0; i < 4; i++)
        #pragma unroll
        for (int j = 0; j < 5; j++)
            acc[i][j] = (f32x4){0.f, 0.f, 0.f, 0.f};

    // per-lane A row pointers (lane mr owns row mt*16+mr; q selects the k-chunk)
    const float* arow[4];
    bool rok[4];
    #pragma unroll
    for (int mt = 0; mt < 4; mt++) {
        int row = m0 + mt * 16 + mr;
        rok[mt]  = row < M;
        arow[mt] = A + (size_t)(row < M ? row : 0) * lda;
    }

    const char* gB = (const char*)Bpk;

    auto loadA = [&](float (&f)[4][8], int ks) {
        const int k0c = ks * 32 + q * 8;
        #pragma unroll
        for (int mt = 0; mt < 4; mt++) {
            if (rok[mt] && (k0c + 8 <= kvalid)) {
                float4 v0 = *(const float4*)(arow[mt] + k0c);
                float4 v1 = *(const float4*)(arow[mt] + k0c + 4);
                f[mt][0]=v0.x; f[mt][1]=v0.y; f[mt][2]=v0.z; f[mt][3]=v0.w;
                f[mt][4]=v1.x; f[mt][5]=v1.y; f[mt][6]=v1.z; f[mt][7]=v1.w;
            } else {
                #pragma unroll
                for (int p = 0; p < 8; p += 2) {
                    int k = k0c + p;
                    float2 t = {0.f, 0.f};
                    if (rok[mt] && k < kvalid) t = *(const float2*)(arow[mt] + k);  // DD even
                    f[mt][p] = t.x; f[mt][p+1] = t.y;
                }
            }
        }
    };

    auto stageB = [&](int buf, int ks) {
        const char* gsrc = gB + (size_t)(ks * BPK_KS) * 2;
        #pragma unroll
        for (int j = 0; j < 10; j++) {
            int chunk = j * 4 + wave;                 // 0..39, wave-uniform base
            gload_lds16(gsrc + chunk * 1024 + lane * 16,
                        (char*)Bs[buf] + chunk * 1024);
        }
    };

    float fcur[4][8], fnext[4][8];

    // prologue: buf0 <- ks0, A(0) in regs
    loadA(fcur, 0);
    stageB(0, 0);
    __syncthreads();

    #pragma unroll
    for (int ks = 0; ks < KSTEPS; ks++) {
        // ---- issue next-step work first (hides under this step's compute)
        if (ks + 1 < KSTEPS) {
            stageB((ks + 1) & 1, ks + 1);
            loadA(fnext, ks + 1);
        }

        // ---- convert A(cur) to hi/lo bf16 in regs
        short8 ah[4], al[4];
        #pragma unroll
        for (int mt = 0; mt < 4; mt++) {
            #pragma unroll
            for (int p = 0; p < 8; p++) {
                unsigned int u  = __float_as_uint(fcur[mt][p]);
                unsigned int uh = (u + 0x8000u) & 0xffff0000u;   // round-half-up bf16
                float l = fcur[mt][p] - __uint_as_float(uh);
                ah[mt][p] = (short)(uh >> 16);
                al[mt][p] = (short)((__float_as_uint(l) + 0x8000u) >> 16);
            }
        }

        // ---- B fragments from LDS (swizzled slots) + 3-pass split MFMA
        const unsigned short* Bc = Bs[ks & 1];
        short8 bh[5], bl[5];
        #pragma unroll
        for (int nt = 0; nt < 5; nt++) {
            int col = nbase + nt * 16 + mr;
            int off = col * 32 + bswz(q, col) * 8;
            bh[nt] = *(const short8*)&Bc[off];
            bl[nt] = *(const short8*)&Bc[10240 + off];
        }
        #pragma unroll
        for (int nt = 0; nt < 5; nt++) {
            #pragma unroll
            for (int mt = 0; mt < 4; mt++) {
                acc[mt][nt] = __builtin_amdgcn_mfma_f32_16x16x32_bf16(ah[mt], bh[nt], acc[mt][nt], 0, 0, 0);
                acc[mt][nt] = __builtin_amdgcn_mfma_f32_16x16x32_bf16(ah[mt], bl[nt], acc[mt][nt], 0, 0, 0);
                acc[mt][nt] = __builtin_amdgcn_mfma_f32_16x16x32_bf16(al[mt], bh[nt], acc[mt][nt], 0, 0, 0);
            }
        }

        // ---- one barrier: drains prefetch (vmcnt0) + orders LDS reads
        __syncthreads();

        #pragma unroll
        for (int mt = 0; mt < 4; mt++)
            #pragma unroll
            for (int p = 0; p < 8; p++)
                fcur[mt][p] = fnext[mt][p];
    }

    // epilogue: C/D layout col=lane&15, row=(lane>>4)*4+reg; zero C pad cols 302/303
    #pragma unroll
    for (int mt = 0; mt < 4; mt++) {
        int row_b = m0 + mt * 16 + q * 4;
        #pragma unroll
        for (int nt = 0; nt < 5; nt++) {
            int col = nbase + nt * 16 + mr;
            if (col > DD + 1) continue;
            #pragma unroll
            for (int r = 0; r < 4; r++) {
                int row = row_b + r;
                if (row >= M) continue;
                float v = acc[mt][nt][r];
                if (col < DD) {
                    C[(size_t)row * GS + col] = v;
                } else if (col == DD) {
                    a_s[row] = v;
                    C[(size_t)row * GS + DD] = 0.f;       // keep pad col zero
                } else {
                    a_d[row] = v;
                    C[(size_t)row * GS + DD + 1] = 0.f;   // keep pad col zero
                }
            }
        }
    }
}

// ---------------------------------------------------------------- tiled SGEMM (final linear)
#define BM 64
#define BN 64
#define BK 16
__global__ __launch_bounds__(256) void k_gemm_nt(const float* __restrict__ A,
                                                 const float* __restrict__ B,
                                                 float* __restrict__ C,
                                                 int M, int N, int K,
                                                 const float* __restrict__ bias,
                                                 int relu_a) {
    __shared__ float As[BK][BM + 4];
    __shared__ float Bs[BK][BN + 4];
    int m0 = blockIdx.y * BM;
    int n0 = blockIdx.x * BN;
    int tid = threadIdx.x;
    int tr = tid >> 4;
    int tc = tid & 15;
    float acc[4][4] = {};
    for (int k0 = 0; k0 < K; k0 += BK) {
        #pragma unroll
        for (int j = 0; j < 4; j++) {
            int e = tid + 256 * j;
            int r = e >> 4;
            int k = e & 15;
            int gk = k0 + k;
            int gm = m0 + r;
            float va = 0.f;
            if (gm < M && gk < K) va = A[(size_t)gm * K + gk];
            if (relu_a) va = fmaxf(va, 0.f);
            As[k][r] = va;
            int gn = n0 + r;
            float vb = 0.f;
            if (gn < N && gk < K) vb = B[(size_t)gn * K + gk];
            Bs[k][r] = vb;
        }
        __syncthreads();
        #pragma unroll
        for (int k = 0; k < BK; k++) {
            float a[4], b[4];
            #pragma unroll
            for (int i = 0; i < 4; i++) a[i] = As[k][tr * 4 + i];
            #pragma unroll
            for (int j = 0; j < 4; j++) b[j] = Bs[k][tc * 4 + j];
            #pragma unroll
            for (int i = 0; i < 4; i++)
                #pragma unroll
                for (int j = 0; j < 4; j++)
                    acc[i][j] += a[i] * b[j];
        }
        __syncthreads();
    }
    #pragma unroll
    for (int i = 0; i < 4; i++) {
        int gm = m0 + tr * 4 + i;
        if (gm >= M) continue;
        #pragma unroll
        for (int j = 0; j < 4; j++) {
            int gn = n0 + tc * 4 + j;
            if (gn < N) {
                float v = acc[i][j];
                if (bias) v += bias[gn];
                C[(size_t)gm * N + gn] = v;
            }
        }
    }
}

// ---------------------------------------------------------------- qp = query @ attW  (thread/output)
__global__ __launch_bounds__(256) void k_qp(const float* __restrict__ query,
                                            const float* __restrict__ attW,
                                            float* __restrict__ qp) {
    int b = blockIdx.y;
    int d = blockIdx.x * 256 + threadIdx.x;
    if (d >= DD) return;
    const float* qrow = query + (size_t)b * QQ;
    float acc = 0.f;
    #pragma unroll 8
    for (int q = 0; q < QQ; q++) acc += qrow[q] * attW[(size_t)q * DD + d];
    qp[(size_t)b * DD + d] = acc;
}

// ---------------------------------------------------------------- softmax-aggregate (wave / dst node)
// float4 gather: rows of h have zeroed pad cols 302/303.
// When qp/sarr given (layer 3), fuses the pooling score: sarr[n] = out_n . qp[batch[n]] / sqrt(Q)
// computed from the in-register output (saves a full 61MB re-read pass).
__global__ __launch_bounds__(256) void k_aggregate(const float* __restrict__ h,
                                                   const float* __restrict__ a_s,
                                                   const float* __restrict__ a_d,
                                                   const int* __restrict__ offs,
                                                   const int* __restrict__ deg,
                                                   const int* __restrict__ esrc,
                                                   const float* __restrict__ bias,
                                                   float* __restrict__ out,
                                                   const float* __restrict__ qp,
                                                   const int* __restrict__ batch,
                                                   float* __restrict__ sarr) {
    int gid = blockIdx.x * blockDim.x + threadIdx.x;
    int n = gid >> 6, lane = gid & 63;
    if (n >= N_NODES) return;
    int beg = offs[n], cnt = deg[n];
    float adn = a_d[n];
    float m = -INFINITY;
    for (int i = lane; i < cnt; i += 64) {
        float e = a_s[esrc[beg + i]] + adn;
        e = (e > 0.f) ? e : NEG_SLOPE * e;
        m = fmaxf(m, e);
    }
    for (int off = 32; off; off >>= 1) m = fmaxf(m, __shfl_xor(m, off));
    float den = 0.f;
    for (int i = lane; i < cnt; i += 64) {
        float e = a_s[esrc[beg + i]] + adn;
        e = (e > 0.f) ? e : NEG_SLOPE * e;
        den += __expf(e - m);
    }
    for (int off = 32; off; off >>= 1) den += __shfl_xor(den, off);
    float inv_den = 1.f / den;

    const int c0 = lane * 4;            // 0..252  (covers cols 0..255)
    const int c1 = 256 + lane * 4;      // lanes 0..11 cover cols 256..303
    const bool has1 = lane < 12;
    float4 A0 = {0.f, 0.f, 0.f, 0.f};
    float4 A1 = {0.f, 0.f, 0.f, 0.f};
    for (int i = 0; i < cnt; i++) {
        int s = esrc[beg + i];
        float e = a_s[s] + adn;
        e = (e > 0.f) ? e : NEG_SLOPE * e;
        float w = __expf(e - m) * inv_den;
        const float* row = h + (size_t)s * GS;
        float4 r0 = *(const float4*)(row + c0);
        A0.x += w * r0.x; A0.y += w * r0.y; A0.z += w * r0.z; A0.w += w * r0.w;
        if (has1) {
            float4 r1 = *(const float4*)(row + c1);
            A1.x += w * r1.x; A1.y += w * r1.y; A1.z += w * r1.z; A1.w += w * r1.w;
        }
    }
    float4 o0, o1 = {0.f, 0.f, 0.f, 0.f};
    {
        float4 b0 = *(const float4*)(bias + c0);      // c0 <= 252: in-bounds
        o0.x = fmaxf(A0.x + b0.x, 0.f);
        o0.y = fmaxf(A0.y + b0.y, 0.f);
        o0.z = fmaxf(A0.z + b0.z, 0.f);
        o0.w = fmaxf(A0.w + b0.w, 0.f);
        *(float4*)(out + (size_t)n * GS + c0) = o0;
    }
    if (lane < 11) {                                  // cols 256..299
        float4 b1 = *(const float4*)(bias + c1);
        o1.x = fmaxf(A1.x + b1.x, 0.f);
        o1.y = fmaxf(A1.y + b1.y, 0.f);
        o1.z = fmaxf(A1.z + b1.z, 0.f);
        o1.w = fmaxf(A1.w + b1.w, 0.f);
        *(float4*)(out + (size_t)n * GS + c1) = o1;
    } else if (lane == 11) {                          // cols 300,301 valid; 302,303 -> 0
        o1.x = fmaxf(A1.x + bias[300], 0.f);
        o1.y = fmaxf(A1.y + bias[301], 0.f);
        o1.z = 0.f;
        o1.w = 0.f;
        *(float4*)(out + (size_t)n * GS + 300) = o1;
    }

    // ---- fused pooling score (layer 3 only)
    if (sarr) {
        const float* qv = qp + (size_t)batch[n] * DD;
        float d = o0.x * qv[c0] + o0.y * qv[c0 + 1] + o0.z * qv[c0 + 2] + o0.w * qv[c0 + 3];
        if (lane < 11)
            d += o1.x * qv[c1] + o1.y * qv[c1 + 1] + o1.z * qv[c1 + 2] + o1.w * qv[c1 + 3];
        else if (lane == 11)
            d += o1.x * qv[300] + o1.y * qv[301];
        for (int off = 32; off; off >>= 1) d += __shfl_xor(d, off);
        if (lane == 0) sarr[n] = d * 0.04082482904638630f;   // 1/sqrt(600)
    }
}

// ---------------------------------------------------------------- pooling pieces
// batch is SORTED -> per-graph bounds via binary search (no atomics).
__global__ void k_gbounds(const int* __restrict__ batch, int* goffs, int* gcnt) {
    __shared__ int bound[BB + 1];
    int b = threadIdx.x;
    if (b <= BB) {
        int lo = 0, hi = N_NODES;
        while (lo < hi) {                 // first i with batch[i] >= b
            int mid = (lo + hi) >> 1;
            if (batch[mid] < b) lo = mid + 1; else hi = mid;
        }
        bound[b] = lo;
    }
    __syncthreads();
    if (b < BB) {
        goffs[b] = bound[b];
        gcnt[b]  = bound[b + 1] - bound[b];
    }
}

// per-graph softmax stats; fused: writes per-node weights wn and zeros pooled[b]
__global__ __launch_bounds__(256) void k_gstats(const float* __restrict__ sarr,
                                                const int* __restrict__ goffs,
                                                const int* __restrict__ gcnt,
                                                float* __restrict__ wn,
                                                float* __restrict__ pooled) {
    int b = blockIdx.x;
    int beg = goffs[b], cnt = gcnt[b];
    __shared__ float red[256];
    float m = -INFINITY;
    for (int i = threadIdx.x; i < cnt; i += 256) m = fmaxf(m, sarr[beg + i]);
    red[threadIdx.x] = m;
    __syncthreads();
    for (int d = 128; d; d >>= 1) {
        if (threadIdx.x < d) red[threadIdx.x] = fmaxf(red[threadIdx.x], red[threadIdx.x + d]);
        __syncthreads();
    }
    m = red[0];
    __syncthreads();
    float den = 0.f;
    for (int i = threadIdx.x; i < cnt; i += 256) den += __expf(sarr[beg + i] - m);
    red[threadIdx.x] = den;
    __syncthreads();
    for (int d = 128; d; d >>= 1) {
        if (threadIdx.x < d) red[threadIdx.x] += red[threadIdx.x + d];
        __syncthreads();
    }
    float dinv = (cnt > 0) ? 1.f / red[0] : 0.f;
    for (int i = threadIdx.x; i < cnt; i += 256)
        wn[beg + i] = __expf(sarr[beg + i] - m) * dinv;
    for (int j = threadIdx.x; j < DD; j += 256)
        pooled[(size_t)b * DD + j] = 0.f;
}

// node-chunk-parallel weighted segment sum (batch sorted; flush at graph boundaries)
__global__ __launch_bounds__(256) void k_poolacc(const float* __restrict__ h, int ld,
                                                 const float* __restrict__ wn,
                                                 const int* __restrict__ batch,
                                                 float* __restrict__ pooled) {
    int c0 = blockIdx.x * PC;
    if (c0 >= N_NODES) return;
    int nmax = N_NODES - c0; if (nmax > PC) nmax = PC;
    __shared__ int   sb[PC];
    __shared__ float sw[PC];
    for (int i = threadIdx.x; i < nmax; i += 256) {
        sb[i] = batch[c0 + i];
        sw[i] = wn[c0 + i];
    }
    __syncthreads();
    int f0 = threadIdx.x, f1 = threadIdx.x + 256;
    float a0 = 0.f, a1 = 0.f;
    int g = sb[0];
    for (int i = 0; i < nmax; i++) {
        int bi = sb[i];
        if (bi != g) {                       // wave-uniform branch
            if (f0 < DD) atomicAdd(&pooled[(size_t)g * DD + f0], a0);
            if (f1 < DD) atomicAdd(&pooled[(size_t)g * DD + f1], a1);
            a0 = 0.f; a1 = 0.f; g = bi;
        }
        float w = sw[i];
        const float* row = h + (size_t)(c0 + i) * ld;
        if (f0 < DD) a0 += w * row[f0];
        if (f1 < DD) a1 += w * row[f1];
    }
    if (f0 < DD) atomicAdd(&pooled[(size_t)g * DD + f0], a0);
    if (f1 < DD) atomicAdd(&pooled[(size_t)g * DD + f1], a1);
}

// ---------------------------------------------------------------- launch
extern "C" void kernel_launch(void* const* d_in, const int* in_sizes, int n_in,
                              void* d_out, int out_size, void* d_ws, size_t ws_size,
                              hipStream_t stream) {
    const float* x        = (const float*)d_in[0];
    const int*   edges    = (const int*)d_in[1];   // [2, E]
    const float* query    = (const float*)d_in[2];
    const int*   batch    = (const int*)d_in[3];
    const float* theta    = (const float*)d_in[4];
    const float* att_src  = (const float*)d_in[5];
    const float* att_dst  = (const float*)d_in[6];
    const float* gat_bias = (const float*)d_in[7];
    const float* attW     = (const float*)d_in[8];
    const float* lin_w    = (const float*)d_in[9];
    const float* lin_b    = (const float*)d_in[10];
    float* out = (float*)d_out;

    char* ws = (char*)d_ws;
    size_t off = 0;
    auto alloc = [&](size_t bytes) -> void* {
        off = (off + 255) & ~(size_t)255;
        void* p = ws + off;
        off += bytes;
        return p;
    };

    float* G    = (float*)alloc((size_t)N_NODES * GS * 4);   // gemm output (padded stride)
    float* P    = (float*)alloc((size_t)N_NODES * GS * 4);   // layer output (padded stride)
    unsigned short* bpk = (unsigned short*)alloc((size_t)KSTEPS * BPK_KS * 2); // packed B, 409.6KB
    float* a_s  = (float*)alloc((size_t)N_NODES * 4);
    float* a_d  = (float*)alloc((size_t)N_NODES * 4);
    float* sarr = (float*)alloc((size_t)N_NODES * 4);
    float* wn   = (float*)alloc((size_t)N_NODES * 4);
    int* deg    = (int*)alloc((size_t)N_NODES * 4);
    int* cursor = (int*)alloc((size_t)N_NODES * 4);
    int* offs   = (int*)alloc((size_t)N_NODES * 4);
    int* esrc   = (int*)alloc((size_t)(N_EDGES + N_NODES) * 4);
    int* partials = (int*)alloc(256 * 4);
    int* gcnt   = (int*)alloc(BB * 4);
    int* goffs  = (int*)alloc(BB * 4);
    float* qp   = (float*)alloc((size_t)BB * DD * 4);
    float* pooled = (float*)alloc((size_t)BB * DD * 4);

    const int* e_src = edges;
    const int* e_dst = edges + N_EDGES;

    const int NB_SCAN = (N_NODES + 255) / 256;   // 196

    // ---- CSR build
    k_deg_init<<<NB_SCAN, 256, 0, stream>>>(deg, cursor);
    k_histogram<<<(N_EDGES + 255) / 256, 256, 0, stream>>>(e_dst, deg);
    k_scan_block<<<NB_SCAN, 256, 0, stream>>>(deg, offs, partials);
    k_scan_partials<<<1, 256, 0, stream>>>(partials, NB_SCAN);
    k_scan_add<<<NB_SCAN, 256, 0, stream>>>(offs, partials);
    k_scatter<<<(N_EDGES + N_NODES + 255) / 256, 256, 0, stream>>>(e_src, e_dst, offs, cursor, esrc);

    // ---- theta hi/lo split (k-major, bank-swizzled) + attvec rows (fused; once, shared across layers)
    k_theta_prep<<<402, 256, 0, stream>>>(theta, att_src, att_dst, bpk);

    // ---- qp (needed by fused layer-3 score)
    {
        dim3 g((DD + 255) / 256, BB);
        k_qp<<<g, 256, 0, stream>>>(query, attW, qp);
    }

    // ---- 3 GAT layers (layer 3 fuses pooling scores)
    int mfma_blocks = (N_NODES + 63) / 64;   // 782
    int wave_blocks = (N_NODES + 3) / 4;
    const float* cur = x;
    int cur_ld = DD;
    for (int layer = 0; layer < 3; layer++) {
        k_mfma_gemm<<<mfma_blocks, 256, 0, stream>>>(cur, cur_ld, bpk, G, a_s, a_d, N_NODES);
        bool last = (layer == 2);
        k_aggregate<<<wave_blocks, 256, 0, stream>>>(G, a_s, a_d, offs, deg, esrc, gat_bias, P,
                                                     last ? qp : (const float*)nullptr,
                                                     last ? batch : (const int*)nullptr,
                                                     last ? sarr : (float*)nullptr);
        cur = P;
        cur_ld = GS;
    }

    // ---- attention pooling + classifier
    k_gbounds<<<1, 256, 0, stream>>>(batch, goffs, gcnt);
    k_gstats<<<BB, 256, 0, stream>>>(sarr, goffs, gcnt, wn, pooled);
    k_poolacc<<<(N_NODES + PC - 1) / PC, 256, 0, stream>>>(P, GS, wn, batch, pooled);
    {
        dim3 g((CC + BN - 1) / BN, (BB + BM - 1) / BM);
        k_gemm_nt<<<g, 256, 0, stream>>>(pooled, lin_w, out, BB, CC, DD, lin_b, 1);
    }
}

// Round 7
// 704.346 us; speedup vs baseline: 1.1164x; 1.0397x over previous
//
#include <hip/hip_runtime.h>
#include <hip/hip_bf16.h>
#include <math.h>

#define N_NODES 50000
#define N_EDGES 250000
#define BB      128
#define DD      302
#define QQ      600
#define CC      2000
#define NEG_SLOPE 0.2f
#define GS      304        // padded row stride for G and P (16B-aligned rows)
#define KP      320        // padded K (10 x 32)
#define KSTEPS  10         // KP / 32
#define PC      64         // nodes per pooling chunk
#define BPK_KS  20480      // shorts per k-step in packed B: [hi 320x32][lo 320x32]

typedef __attribute__((ext_vector_type(8))) short short8;
typedef __attribute__((ext_vector_type(4))) float f32x4;

__device__ __forceinline__ void gload_lds16(const void* g, void* l) {
    __builtin_amdgcn_global_load_lds((const __attribute__((address_space(1))) void*)g,
                                     (__attribute__((address_space(3))) void*)l, 16, 0, 0);
}

// bank-spread slot for packed B: 2 lanes/bank on ds_read_b128 (free per m136)
__device__ __host__ __forceinline__ int bswz(int q, int n) {
    return q ^ (n & 3) ^ ((n >> 2) & 3);
}

// ---------------------------------------------------------------- CSR build
// deg = pure in-edge histogram (memset to 0); self-loop slot is implicit:
// node n owns esrc slots [offs[n]+partials[n>>8]+n, ... + deg[n]] (deg[n]+1 slots).
__global__ void k_histogram(const int* __restrict__ dst, int* deg) {
    int e = blockIdx.x * blockDim.x + threadIdx.x;
    if (e < N_EDGES) atomicAdd(&deg[dst[e]], 1);
}

__global__ void k_scan_block(const int* __restrict__ deg, int* offs, int* partials) {
    __shared__ int sh[256];
    int i = blockIdx.x * 256 + threadIdx.x;
    int v = (i < N_NODES) ? deg[i] : 0;
    sh[threadIdx.x] = v;
    __syncthreads();
    for (int d = 1; d < 256; d <<= 1) {
        int t = (threadIdx.x >= d) ? sh[threadIdx.x - d] : 0;
        __syncthreads();
        sh[threadIdx.x] += t;
        __syncthreads();
    }
    if (i < N_NODES) offs[i] = sh[threadIdx.x] - v;   // exclusive (block-local)
    if (threadIdx.x == 255) partials[blockIdx.x] = sh[255];
}

__global__ void k_scan_partials(int* partials, int nb) {
    __shared__ int sh[256];
    int v = (threadIdx.x < nb) ? partials[threadIdx.x] : 0;
    sh[threadIdx.x] = v;
    __syncthreads();
    for (int d = 1; d < 256; d <<= 1) {
        int t = (threadIdx.x >= d) ? sh[threadIdx.x - d] : 0;
        __syncthreads();
        sh[threadIdx.x] += t;
        __syncthreads();
    }
    if (threadIdx.x < nb) partials[threadIdx.x] = sh[threadIdx.x] - v;  // exclusive
}

__global__ void k_scatter(const int* __restrict__ src, const int* __restrict__ dst,
                          const int* __restrict__ offs, const int* __restrict__ partials,
                          const int* __restrict__ deg, int* cursor, int* esrc) {
    int i = blockIdx.x * blockDim.x + threadIdx.x;
    if (i < N_EDGES) {
        int d = dst[i];
        int base = offs[d] + partials[d >> 8] + d;
        int pos = base + atomicAdd(&cursor[d], 1);
        esrc[pos] = src[i];
    } else if (i < N_EDGES + N_NODES) {
        int n = i - N_EDGES;
        int base = offs[n] + partials[n >> 8] + n;
        esrc[base + deg[n]] = n;   // self loop in the last slot (deg final before this kernel)
    }
}

// ---------------------------------------------------------------- theta -> k-major packed hi/lo bf16 (+attvec rows +qp)
// bpk layout per k-step ks (40KB): [hi: 320 rows x 4 slots x 8 k][lo: same].
// Blocks [0,400): theta rows (skip DD/DD+1).  Blocks [400,402): attvec rows
// DD/DD+1 for all k (zeros for k>=DD).  Blocks [402,658): qp = query @ attW.
__global__ void k_theta_prep(const float* __restrict__ theta,
                             const float* __restrict__ att_src,
                             const float* __restrict__ att_dst,
                             unsigned short* __restrict__ bpk,
                             const float* __restrict__ query,
                             float* __restrict__ qp) {
    if (blockIdx.x >= 402) {                          // ---- qp branch
        int t = blockIdx.x - 402;                     // 0..255
        int b = t >> 1;
        int d = (t & 1) * 256 + threadIdx.x;
        if (d >= DD) return;
        const float* qrow = query + (size_t)b * QQ;
        float acc = 0.f;
        #pragma unroll 8
        for (int q = 0; q < QQ; q++) acc += qrow[q] * qp[0 * 0] * 0.f + qrow[q] * 0.f; // placeholder never used
        // NOTE: replaced below — see real implementation
        return;
    }
    if (blockIdx.x >= 400) {
        int k = (blockIdx.x - 400) * 256 + threadIdx.x;
        if (k >= KP) return;
        float vs = 0.f, vd = 0.f;
        if (k < DD) {
            for (int j = 0; j < DD; j++) {
                float t = theta[j * DD + k];      // coalesced over k
                vs += t * att_src[j];
                vd += t * att_dst[j];
            }
        }
        int ks = k >> 5, kk = k & 31, q = kk >> 3, kb = kk & 7;
        size_t b0 = (size_t)ks * BPK_KS + DD * 32 + bswz(q, DD) * 8 + kb;
        size_t b1 = (size_t)ks * BPK_KS + (DD + 1) * 32 + bswz(q, DD + 1) * 8 + kb;
        unsigned int u, uh, ul;
        u  = __float_as_uint(vs);
        uh = (u + 0x8000u) & 0xffff0000u;
        ul = (__float_as_uint(vs - __uint_as_float(uh)) + 0x8000u) >> 16;
        bpk[b0]         = (unsigned short)(uh >> 16);
        bpk[b0 + 10240] = (unsigned short)ul;
        u  = __float_as_uint(vd);
        uh = (u + 0x8000u) & 0xffff0000u;
        ul = (__float_as_uint(vd - __uint_as_float(uh)) + 0x8000u) >> 16;
        bpk[b1]         = (unsigned short)(uh >> 16);
        bpk[b1 + 10240] = (unsigned short)ul;
        return;
    }
    int idx = blockIdx.x * 256 + threadIdx.x;
    if (idx >= KP * KP) return;
    int n = idx / KP, k = idx % KP;
    if (n == DD || n == DD + 1) return;               // attvec rows owned by blocks >=400
    float v = (n < DD && k < DD) ? theta[n * DD + k] : 0.f;
    unsigned int u  = __float_as_uint(v);
    unsigned int uh = (u + 0x8000u) & 0xffff0000u;    // round-half-up bf16
    float hf = __uint_as_float(uh);
    float lo = v - hf;
    unsigned int ul = (__float_as_uint(lo) + 0x8000u) >> 16;
    int ks = k >> 5, kk = k & 31, q = kk >> 3, kb = kk & 7;
    size_t base = (size_t)ks * BPK_KS + n * 32 + bswz(q, n) * 8 + kb;
    bpk[base]         = (unsigned short)(uh >> 16);
    bpk[base + 10240] = (unsigned short)ul;
}

// real qp kernel branch (kept separate for clarity of the fused dispatch):
// implemented inside k_theta_prep via the attW pointer
__global__ void k_theta_qp(const float* __restrict__ theta,
                           const float* __restrict__ att_src,
                           const float* __restrict__ att_dst,
                           unsigned short* __restrict__ bpk,
                           const float* __restrict__ query,
                           const float* __restrict__ attW,
                           float* __restrict__ qp) {
    if (blockIdx.x >= 402) {                          // ---- qp branch
        int t = blockIdx.x - 402;                     // 0..255
        int b = t >> 1;
        int d = (t & 1) * 256 + threadIdx.x;
        if (d >= DD) return;
        const float* qrow = query + (size_t)b * QQ;
        float acc = 0.f;
        #pragma unroll 8
        for (int q = 0; q < QQ; q++) acc += qrow[q] * attW[(size_t)q * DD + d];
        qp[(size_t)b * DD + d] = acc;
        return;
    }
    if (blockIdx.x >= 400) {
        int k = (blockIdx.x - 400) * 256 + threadIdx.x;
        if (k >= KP) return;
        float vs = 0.f, vd = 0.f;
        if (k < DD) {
            for (int j = 0; j < DD; j++) {
                float t = theta[j * DD + k];
                vs += t * att_src[j];
                vd += t * att_dst[j];
            }
        }
        int ks = k >> 5, kk = k & 31, q = kk >> 3, kb = kk & 7;
        size_t b0 = (size_t)ks * BPK_KS + DD * 32 + bswz(q, DD) * 8 + kb;
        size_t b1 = (size_t)ks * BPK_KS + (DD + 1) * 32 + bswz(q, DD + 1) * 8 + kb;
        unsigned int u, uh, ul;
        u  = __float_as_uint(vs);
        uh = (u + 0x8000u) & 0xffff0000u;
        ul = (__float_as_uint(vs - __uint_as_float(uh)) + 0x8000u) >> 16;
        bpk[b0]         = (unsigned short)(uh >> 16);
        bpk[b0 + 10240] = (unsigned short)ul;
        u  = __float_as_uint(vd);
        uh = (u + 0x8000u) & 0xffff0000u;
        ul = (__float_as_uint(vd - __uint_as_float(uh)) + 0x8000u) >> 16;
        bpk[b1]         = (unsigned short)(uh >> 16);
        bpk[b1 + 10240] = (unsigned short)ul;
        return;
    }
    int idx = blockIdx.x * 256 + threadIdx.x;
    if (idx >= KP * KP) return;
    int n = idx / KP, k = idx % KP;
    if (n == DD || n == DD + 1) return;
    float v = (n < DD && k < DD) ? theta[n * DD + k] : 0.f;
    unsigned int u  = __float_as_uint(v);
    unsigned int uh = (u + 0x8000u) & 0xffff0000u;    // round-half-up bf16
    float hf = __uint_as_float(uh);
    float lo = v - hf;
    unsigned int ul = (__float_as_uint(lo) + 0x8000u) >> 16;
    int ks = k >> 5, kk = k & 31, q = kk >> 3, kb = kk & 7;
    size_t base = (size_t)ks * BPK_KS + n * 32 + bswz(q, n) * 8 + kb;
    bpk[base]         = (unsigned short)(uh >> 16);
    bpk[base + 10240] = (unsigned short)ul;
}

// ---------------------------------------------------------------- split-bf16 MFMA GEMM
// (unchanged from R6 — verified passing)
__global__ __launch_bounds__(256) void k_mfma_gemm(const float* __restrict__ A, int lda,
                                                   const unsigned short* __restrict__ Bpk,
                                                   float* __restrict__ C,
                                                   float* __restrict__ a_s,
                                                   float* __restrict__ a_d, int M) {
    __shared__ __attribute__((aligned(16))) unsigned short Bs[2][BPK_KS]; // 80KB

    const int tid   = threadIdx.x;
    const int lane  = tid & 63;
    const int wave  = tid >> 6;         // 0..3
    const int q     = lane >> 4;        // 0..3
    const int mr    = lane & 15;
    const int m0    = blockIdx.x * 64;
    const int nbase = wave * 80;
    const int kvalid = (lda == GS) ? GS : DD;   // readable floats per A row

    f32x4 acc[4][5];
    #pragma unroll
    for (int i = 0; i < 4; i++)
        #pragma unroll
        for (int j = 0; j < 5; j++)
            acc[i][j] = (f32x4){0.f, 0.f, 0.f, 0.f};

    const float* arow[4];
    bool rok[4];
    #pragma unroll
    for (int mt = 0; mt < 4; mt++) {
        int row = m0 + mt * 16 + mr;
        rok[mt]  = row < M;
        arow[mt] = A + (size_t)(row < M ? row : 0) * lda;
    }

    const char* gB = (const char*)Bpk;

    auto loadA = [&](float (&f)[4][8], int ks) {
        const int k0c = ks * 32 + q * 8;
        #pragma unroll
        for (int mt = 0; mt < 4; mt++) {
            if (rok[mt] && (k0c + 8 <= kvalid)) {
                float4 v0 = *(const float4*)(arow[mt] + k0c);
                float4 v1 = *(const float4*)(arow[mt] + k0c + 4);
                f[mt][0]=v0.x; f[mt][1]=v0.y; f[mt][2]=v0.z; f[mt][3]=v0.w;
                f[mt][4]=v1.x; f[mt][5]=v1.y; f[mt][6]=v1.z; f[mt][7]=v1.w;
            } else {
                #pragma unroll
                for (int p = 0; p < 8; p += 2) {
                    int k = k0c + p;
                    float2 t = {0.f, 0.f};
                    if (rok[mt] && k < kvalid) t = *(const float2*)(arow[mt] + k);  // DD even
                    f[mt][p] = t.x; f[mt][p+1] = t.y;
                }
            }
        }
    };

    auto stageB = [&](int buf, int ks) {
        const char* gsrc = gB + (size_t)(ks * BPK_KS) * 2;
        #pragma unroll
        for (int j = 0; j < 10; j++) {
            int chunk = j * 4 + wave;                 // 0..39, wave-uniform base
            gload_lds16(gsrc + chunk * 1024 + lane * 16,
                        (char*)Bs[buf] + chunk * 1024);
        }
    };

    float fcur[4][8], fnext[4][8];

    loadA(fcur, 0);
    stageB(0, 0);
    __syncthreads();

    #pragma unroll
    for (int ks = 0; ks < KSTEPS; ks++) {
        if (ks + 1 < KSTEPS) {
            stageB((ks + 1) & 1, ks + 1);
            loadA(fnext, ks + 1);
        }

        short8 ah[4], al[4];
        #pragma unroll
        for (int mt = 0; mt < 4; mt++) {
            #pragma unroll
            for (int p = 0; p < 8; p++) {
                unsigned int u  = __float_as_uint(fcur[mt][p]);
                unsigned int uh = (u + 0x8000u) & 0xffff0000u;   // round-half-up bf16
                float l = fcur[mt][p] - __uint_as_float(uh);
                ah[mt][p] = (short)(uh >> 16);
                al[mt][p] = (short)((__float_as_uint(l) + 0x8000u) >> 16);
            }
        }

        const unsigned short* Bc = Bs[ks & 1];
        short8 bh[5], bl[5];
        #pragma unroll
        for (int nt = 0; nt < 5; nt++) {
            int col = nbase + nt * 16 + mr;
            int off = col * 32 + bswz(q, col) * 8;
            bh[nt] = *(const short8*)&Bc[off];
            bl[nt] = *(const short8*)&Bc[10240 + off];
        }
        #pragma unroll
        for (int nt = 0; nt < 5; nt++) {
            #pragma unroll
            for (int mt = 0; mt < 4; mt++) {
                acc[mt][nt] = __builtin_amdgcn_mfma_f32_16x16x32_bf16(ah[mt], bh[nt], acc[mt][nt], 0, 0, 0);
                acc[mt][nt] = __builtin_amdgcn_mfma_f32_16x16x32_bf16(ah[mt], bl[nt], acc[mt][nt], 0, 0, 0);
                acc[mt][nt] = __builtin_amdgcn_mfma_f32_16x16x32_bf16(al[mt], bh[nt], acc[mt][nt], 0, 0, 0);
            }
        }

        __syncthreads();

        #pragma unroll
        for (int mt = 0; mt < 4; mt++)
            #pragma unroll
            for (int p = 0; p < 8; p++)
                fcur[mt][p] = fnext[mt][p];
    }

    #pragma unroll
    for (int mt = 0; mt < 4; mt++) {
        int row_b = m0 + mt * 16 + q * 4;
        #pragma unroll
        for (int nt = 0; nt < 5; nt++) {
            int col = nbase + nt * 16 + mr;
            if (col > DD + 1) continue;
            #pragma unroll
            for (int r = 0; r < 4; r++) {
                int row = row_b + r;
                if (row >= M) continue;
                float v = acc[mt][nt][r];
                if (col < DD) {
                    C[(size_t)row * GS + col] = v;
                } else if (col == DD) {
                    a_s[row] = v;
                    C[(size_t)row * GS + DD] = 0.f;
                } else {
                    a_d[row] = v;
                    C[(size_t)row * GS + DD + 1] = 0.f;
                }
            }
        }
    }
}

// ---------------------------------------------------------------- tiled SGEMM (final linear)
#define BM 64
#define BN 64
#define BK 16
__global__ __launch_bounds__(256) void k_gemm_nt(const float* __restrict__ A,
                                                 const float* __restrict__ B,
                                                 float* __restrict__ C,
                                                 int M, int N, int K,
                                                 const float* __restrict__ bias,
                                                 int relu_a) {
    __shared__ float As[BK][BM + 4];
    __shared__ float Bs[BK][BN + 4];
    int m0 = blockIdx.y * BM;
    int n0 = blockIdx.x * BN;
    int tid = threadIdx.x;
    int tr = tid >> 4;
    int tc = tid & 15;
    float acc[4][4] = {};
    for (int k0 = 0; k0 < K; k0 += BK) {
        #pragma unroll
        for (int j = 0; j < 4; j++) {
            int e = tid + 256 * j;
            int r = e >> 4;
            int k = e & 15;
            int gk = k0 + k;
            int gm = m0 + r;
            float va = 0.f;
            if (gm < M && gk < K) va = A[(size_t)gm * K + gk];
            if (relu_a) va = fmaxf(va, 0.f);
            As[k][r] = va;
            int gn = n0 + r;
            float vb = 0.f;
            if (gn < N && gk < K) vb = B[(size_t)gn * K + gk];
            Bs[k][r] = vb;
        }
        __syncthreads();
        #pragma unroll
        for (int k = 0; k < BK; k++) {
            float a[4], b[4];
            #pragma unroll
            for (int i = 0; i < 4; i++) a[i] = As[k][tr * 4 + i];
            #pragma unroll
            for (int j = 0; j < 4; j++) b[j] = Bs[k][tc * 4 + j];
            #pragma unroll
            for (int i = 0; i < 4; i++)
                #pragma unroll
                for (int j = 0; j < 4; j++)
                    acc[i][j] += a[i] * b[j];
        }
        __syncthreads();
    }
    #pragma unroll
    for (int i = 0; i < 4; i++) {
        int gm = m0 + tr * 4 + i;
        if (gm >= M) continue;
        #pragma unroll
        for (int j = 0; j < 4; j++) {
            int gn = n0 + tc * 4 + j;
            if (gn < N) {
                float v = acc[i][j];
                if (bias) v += bias[gn];
                C[(size_t)gm * N + gn] = v;
            }
        }
    }
}

// ---------------------------------------------------------------- softmax-aggregate (wave / dst node)
// Online-softmax (single stats pass) + weighted float4 gather.
// base = offs[n]+partials[n>>8]+n, cnt = deg[n]+1 (implicit self-loop slot).
__global__ __launch_bounds__(256) void k_aggregate(const float* __restrict__ h,
                                                   const float* __restrict__ a_s,
                                                   const float* __restrict__ a_d,
                                                   const int* __restrict__ offs,
                                                   const int* __restrict__ partials,
                                                   const int* __restrict__ deg,
                                                   const int* __restrict__ esrc,
                                                   const float* __restrict__ bias,
                                                   float* __restrict__ out,
                                                   const float* __restrict__ qp,
                                                   const int* __restrict__ batch,
                                                   float* __restrict__ sarr) {
    int gid = blockIdx.x * blockDim.x + threadIdx.x;
    int n = gid >> 6, lane = gid & 63;
    if (n >= N_NODES) return;
    int beg = offs[n] + partials[n >> 8] + n;
    int cnt = deg[n] + 1;
    float adn = a_d[n];

    // ---- online softmax stats (one pass; finite sentinel avoids inf-inf NaN)
    float m = -1.0e30f, den = 0.f;
    for (int i = lane; i < cnt; i += 64) {
        float e = a_s[esrc[beg + i]] + adn;
        e = (e > 0.f) ? e : NEG_SLOPE * e;
        float nm = fmaxf(m, e);
        den = den * __expf(m - nm) + __expf(e - nm);
        m = nm;
    }
    for (int off = 32; off; off >>= 1) {
        float mo = __shfl_xor(m, off);
        float dn = __shfl_xor(den, off);
        float nm = fmaxf(m, mo);
        den = den * __expf(m - nm) + dn * __expf(mo - nm);
        m = nm;
    }
    float inv_den = 1.f / den;

    const int c0 = lane * 4;            // 0..252  (covers cols 0..255)
    const int c1 = 256 + lane * 4;      // lanes 0..11 cover cols 256..303
    const bool has1 = lane < 12;
    float4 A0 = {0.f, 0.f, 0.f, 0.f};
    float4 A1 = {0.f, 0.f, 0.f, 0.f};
    #pragma unroll 2
    for (int i = 0; i < cnt; i++) {
        int s = esrc[beg + i];
        float e = a_s[s] + adn;
        e = (e > 0.f) ? e : NEG_SLOPE * e;
        float w = __expf(e - m) * inv_den;
        const float* row = h + (size_t)s * GS;
        float4 r0 = *(const float4*)(row + c0);
        A0.x += w * r0.x; A0.y += w * r0.y; A0.z += w * r0.z; A0.w += w * r0.w;
        if (has1) {
            float4 r1 = *(const float4*)(row + c1);
            A1.x += w * r1.x; A1.y += w * r1.y; A1.z += w * r1.z; A1.w += w * r1.w;
        }
    }
    float4 o0, o1 = {0.f, 0.f, 0.f, 0.f};
    {
        float4 b0 = *(const float4*)(bias + c0);      // c0 <= 252: in-bounds
        o0.x = fmaxf(A0.x + b0.x, 0.f);
        o0.y = fmaxf(A0.y + b0.y, 0.f);
        o0.z = fmaxf(A0.z + b0.z, 0.f);
        o0.w = fmaxf(A0.w + b0.w, 0.f);
        *(float4*)(out + (size_t)n * GS + c0) = o0;
    }
    if (lane < 11) {                                  // cols 256..299
        float4 b1 = *(const float4*)(bias + c1);
        o1.x = fmaxf(A1.x + b1.x, 0.f);
        o1.y = fmaxf(A1.y + b1.y, 0.f);
        o1.z = fmaxf(A1.z + b1.z, 0.f);
        o1.w = fmaxf(A1.w + b1.w, 0.f);
        *(float4*)(out + (size_t)n * GS + c1) = o1;
    } else if (lane == 11) {                          // cols 300,301 valid; 302,303 -> 0
        o1.x = fmaxf(A1.x + bias[300], 0.f);
        o1.y = fmaxf(A1.y + bias[301], 0.f);
        o1.z = 0.f;
        o1.w = 0.f;
        *(float4*)(out + (size_t)n * GS + 300) = o1;
    }

    // ---- fused pooling score (layer 3 only)
    if (sarr) {
        const float* qv = qp + (size_t)batch[n] * DD;
        float d = o0.x * qv[c0] + o0.y * qv[c0 + 1] + o0.z * qv[c0 + 2] + o0.w * qv[c0 + 3];
        if (lane < 11)
            d += o1.x * qv[c1] + o1.y * qv[c1 + 1] + o1.z * qv[c1 + 2] + o1.w * qv[c1 + 3];
        else if (lane == 11)
            d += o1.x * qv[300] + o1.y * qv[301];
        for (int off = 32; off; off >>= 1) d += __shfl_xor(d, off);
        if (lane == 0) sarr[n] = d * 0.04082482904638630f;   // 1/sqrt(600)
    }
}

// ---------------------------------------------------------------- pooling pieces
// per-graph softmax stats; fused: inline bounds search, writes wn, zeros pooled[b]
__global__ __launch_bounds__(256) void k_gstats(const float* __restrict__ sarr,
                                                const int* __restrict__ batch,
                                                float* __restrict__ wn,
                                                float* __restrict__ pooled) {
    int b = blockIdx.x;
    int lo = 0, hi = N_NODES;
    while (lo < hi) { int mid = (lo + hi) >> 1; if (batch[mid] < b) lo = mid + 1; else hi = mid; }
    int beg = lo;
    hi = N_NODES;
    while (lo < hi) { int mid = (lo + hi) >> 1; if (batch[mid] < b + 1) lo = mid + 1; else hi = mid; }
    int cnt = lo - beg;

    __shared__ float red[256];
    float m = -INFINITY;
    for (int i = threadIdx.x; i < cnt; i += 256) m = fmaxf(m, sarr[beg + i]);
    red[threadIdx.x] = m;
    __syncthreads();
    for (int d = 128; d; d >>= 1) {
        if (threadIdx.x < d) red[threadIdx.x] = fmaxf(red[threadIdx.x], red[threadIdx.x + d]);
        __syncthreads();
    }
    m = red[0];
    __syncthreads();
    float den = 0.f;
    for (int i = threadIdx.x; i < cnt; i += 256) den += __expf(sarr[beg + i] - m);
    red[threadIdx.x] = den;
    __syncthreads();
    for (int d = 128; d; d >>= 1) {
        if (threadIdx.x < d) red[threadIdx.x] += red[threadIdx.x + d];
        __syncthreads();
    }
    float dinv = (cnt > 0) ? 1.f / red[0] : 0.f;
    for (int i = threadIdx.x; i < cnt; i += 256)
        wn[beg + i] = __expf(sarr[beg + i] - m) * dinv;
    for (int j = threadIdx.x; j < DD; j += 256)
        pooled[(size_t)b * DD + j] = 0.f;
}

// node-chunk-parallel weighted segment sum (batch sorted; flush at graph boundaries)
__global__ __launch_bounds__(256) void k_poolacc(const float* __restrict__ h, int ld,
                                                 const float* __restrict__ wn,
                                                 const int* __restrict__ batch,
                                                 float* __restrict__ pooled) {
    int c0 = blockIdx.x * PC;
    if (c0 >= N_NODES) return;
    int nmax = N_NODES - c0; if (nmax > PC) nmax = PC;
    __shared__ int   sb[PC];
    __shared__ float sw[PC];
    for (int i = threadIdx.x; i < nmax; i += 256) {
        sb[i] = batch[c0 + i];
        sw[i] = wn[c0 + i];
    }
    __syncthreads();
    int f0 = threadIdx.x, f1 = threadIdx.x + 256;
    float a0 = 0.f, a1 = 0.f;
    int g = sb[0];
    for (int i = 0; i < nmax; i++) {
        int bi = sb[i];
        if (bi != g) {                       // wave-uniform branch
            if (f0 < DD) atomicAdd(&pooled[(size_t)g * DD + f0], a0);
            if (f1 < DD) atomicAdd(&pooled[(size_t)g * DD + f1], a1);
            a0 = 0.f; a1 = 0.f; g = bi;
        }
        float w = sw[i];
        const float* row = h + (size_t)(c0 + i) * ld;
        if (f0 < DD) a0 += w * row[f0];
        if (f1 < DD) a1 += w * row[f1];
    }
    if (f0 < DD) atomicAdd(&pooled[(size_t)g * DD + f0], a0);
    if (f1 < DD) atomicAdd(&pooled[(size_t)g * DD + f1], a1);
}

// ---------------------------------------------------------------- launch
extern "C" void kernel_launch(void* const* d_in, const int* in_sizes, int n_in,
                              void* d_out, int out_size, void* d_ws, size_t ws_size,
                              hipStream_t stream) {
    const float* x        = (const float*)d_in[0];
    const int*   edges    = (const int*)d_in[1];   // [2, E]
    const float* query    = (const float*)d_in[2];
    const int*   batch    = (const int*)d_in[3];
    const float* theta    = (const float*)d_in[4];
    const float* att_src  = (const float*)d_in[5];
    const float* att_dst  = (const float*)d_in[6];
    const float* gat_bias = (const float*)d_in[7];
    const float* attW     = (const float*)d_in[8];
    const float* lin_w    = (const float*)d_in[9];
    const float* lin_b    = (const float*)d_in[10];
    float* out = (float*)d_out;

    char* ws = (char*)d_ws;
    size_t off = 0;
    auto alloc = [&](size_t bytes) -> void* {
        off = (off + 255) & ~(size_t)255;
        void* p = ws + off;
        off += bytes;
        return p;
    };

    float* G    = (float*)alloc((size_t)N_NODES * GS * 4);   // gemm output (padded stride)
    float* P    = (float*)alloc((size_t)N_NODES * GS * 4);   // layer output (padded stride)
    unsigned short* bpk = (unsigned short*)alloc((size_t)KSTEPS * BPK_KS * 2); // packed B, 409.6KB
    float* a_s  = (float*)alloc((size_t)N_NODES * 4);
    float* a_d  = (float*)alloc((size_t)N_NODES * 4);
    float* sarr = (float*)alloc((size_t)N_NODES * 4);
    float* wn   = (float*)alloc((size_t)N_NODES * 4);
    int* deg    = (int*)alloc((size_t)N_NODES * 4);
    int* cursor = (int*)alloc((size_t)N_NODES * 4);
    int* offs   = (int*)alloc((size_t)N_NODES * 4);
    int* esrc   = (int*)alloc((size_t)(N_EDGES + N_NODES) * 4);
    int* partials = (int*)alloc(256 * 4);
    float* qp   = (float*)alloc((size_t)BB * DD * 4);
    float* pooled = (float*)alloc((size_t)BB * DD * 4);

    const int* e_src = edges;
    const int* e_dst = edges + N_EDGES;

    const int NB_SCAN = (N_NODES + 255) / 256;   // 196

    // ---- CSR build (deg/cursor zeroed via async memset; self-loop slot implicit)
    hipMemsetAsync(deg, 0, (size_t)N_NODES * 4, stream);
    hipMemsetAsync(cursor, 0, (size_t)N_NODES * 4, stream);
    k_histogram<<<(N_EDGES + 255) / 256, 256, 0, stream>>>(e_dst, deg);
    k_scan_block<<<NB_SCAN, 256, 0, stream>>>(deg, offs, partials);
    k_scan_partials<<<1, 256, 0, stream>>>(partials, NB_SCAN);
    k_scatter<<<(N_EDGES + N_NODES + 255) / 256, 256, 0, stream>>>(e_src, e_dst, offs, partials, deg, cursor, esrc);

    // ---- theta hi/lo split + attvec rows + qp (one fused dispatch)
    k_theta_qp<<<658, 256, 0, stream>>>(theta, att_src, att_dst, bpk, query, attW, qp);

    // ---- 3 GAT layers (layer 3 fuses pooling scores)
    int mfma_blocks = (N_NODES + 63) / 64;   // 782
    int wave_blocks = (N_NODES + 3) / 4;
    const float* cur = x;
    int cur_ld = DD;
    for (int layer = 0; layer < 3; layer++) {
        k_mfma_gemm<<<mfma_blocks, 256, 0, stream>>>(cur, cur_ld, bpk, G, a_s, a_d, N_NODES);
        bool last = (layer == 2);
        k_aggregate<<<wave_blocks, 256, 0, stream>>>(G, a_s, a_d, offs, partials, deg, esrc, gat_bias, P,
                                                     last ? qp : (const float*)nullptr,
                                                     last ? batch : (const int*)nullptr,
                                                     last ? sarr : (float*)nullptr);
        cur = P;
        cur_ld = GS;
    }

    // ---- attention pooling + classifier
    k_gstats<<<BB, 256, 0, stream>>>(sarr, batch, wn, pooled);
    k_poolacc<<<(N_NODES + PC - 1) / PC, 256, 0, stream>>>(P, GS, wn, batch, pooled);
    {
        dim3 g((CC + BN - 1) / BN, (BB + BM - 1) / BM);
        k_gemm_nt<<<g, 256, 0, stream>>>(pooled, lin_w, out, BB, CC, DD, lin_b, 1);
    }
}

// Round 9
// 697.392 us; speedup vs baseline: 1.1275x; 1.0100x over previous
//
#include <hip/hip_runtime.h>
#include <hip/hip_bf16.h>
#include <math.h>

#define N_NODES 50000
#define N_EDGES 250000
#define BB      128
#define DD      302
#define QQ      600
#define CC      2000
#define NEG_SLOPE 0.2f
#define GS      304        // padded row stride for G and P (16B-aligned rows)
#define KP      320        // padded K (10 x 32)
#define KSTEPS  10         // KP / 32
#define PC      64         // nodes per pooling chunk
#define BPK_KS  20480      // shorts per k-step in packed B: [hi 320x32][lo 320x32]

typedef __attribute__((ext_vector_type(8))) short short8;
typedef __attribute__((ext_vector_type(4))) float f32x4;

__device__ __forceinline__ void gload_lds16(const void* g, void* l) {
    __builtin_amdgcn_global_load_lds((const __attribute__((address_space(1))) void*)g,
                                     (__attribute__((address_space(3))) void*)l, 16, 0, 0);
}

// bank-spread slot for packed B: 2 lanes/bank on ds_read_b128 (free per m136)
__device__ __host__ __forceinline__ int bswz(int q, int n) {
    return q ^ (n & 3) ^ ((n >> 2) & 3);
}

__device__ __forceinline__ unsigned short f2bf(float v) {   // round-half-up bf16
    return (unsigned short)((__float_as_uint(v) + 0x8000u) >> 16);
}
__device__ __forceinline__ float bf2f(unsigned short u) {
    return __uint_as_float(((unsigned int)u) << 16);
}

// ---------------------------------------------------------------- CSR build
// deg = pure in-edge histogram; self-loop slot is implicit:
// node n owns esrc slots [offs[n]+partials[n>>8]+n, ... + deg[n]] (deg[n]+1 slots).
__global__ void k_zero_dc(int* deg, int* cursor) {
    int i = blockIdx.x * 256 + threadIdx.x;
    if (i < N_NODES) { deg[i] = 0; cursor[i] = 0; }
}

__global__ void k_histogram(const int* __restrict__ dst, int* deg) {
    int e = blockIdx.x * blockDim.x + threadIdx.x;
    if (e < N_EDGES) atomicAdd(&deg[dst[e]], 1);
}

__global__ void k_scan_block(const int* __restrict__ deg, int* offs, int* partials) {
    __shared__ int sh[256];
    int i = blockIdx.x * 256 + threadIdx.x;
    int v = (i < N_NODES) ? deg[i] : 0;
    sh[threadIdx.x] = v;
    __syncthreads();
    for (int d = 1; d < 256; d <<= 1) {
        int t = (threadIdx.x >= d) ? sh[threadIdx.x - d] : 0;
        __syncthreads();
        sh[threadIdx.x] += t;
        __syncthreads();
    }
    if (i < N_NODES) offs[i] = sh[threadIdx.x] - v;   // exclusive (block-local)
    if (threadIdx.x == 255) partials[blockIdx.x] = sh[255];
}

__global__ void k_scan_partials(int* partials, int nb) {
    __shared__ int sh[256];
    int v = (threadIdx.x < nb) ? partials[threadIdx.x] : 0;
    sh[threadIdx.x] = v;
    __syncthreads();
    for (int d = 1; d < 256; d <<= 1) {
        int t = (threadIdx.x >= d) ? sh[threadIdx.x - d] : 0;
        __syncthreads();
        sh[threadIdx.x] += t;
        __syncthreads();
    }
    if (threadIdx.x < nb) partials[threadIdx.x] = sh[threadIdx.x] - v;  // exclusive
}

__global__ void k_scatter(const int* __restrict__ src, const int* __restrict__ dst,
                          const int* __restrict__ offs, const int* __restrict__ partials,
                          const int* __restrict__ deg, int* cursor, int* esrc) {
    int i = blockIdx.x * blockDim.x + threadIdx.x;
    if (i < N_EDGES) {
        int d = dst[i];
        int base = offs[d] + partials[d >> 8] + d;
        int pos = base + atomicAdd(&cursor[d], 1);
        esrc[pos] = src[i];
    } else if (i < N_EDGES + N_NODES) {
        int n = i - N_EDGES;
        int base = offs[n] + partials[n >> 8] + n;
        esrc[base + deg[n]] = n;   // self loop in the last slot (deg final before this kernel)
    }
}

// ---------------------------------------------------------------- theta pack + attvec rows + qp (one dispatch)
__global__ void k_theta_qp(const float* __restrict__ theta,
                           const float* __restrict__ att_src,
                           const float* __restrict__ att_dst,
                           unsigned short* __restrict__ bpk,
                           const float* __restrict__ query,
                           const float* __restrict__ attW,
                           float* __restrict__ qp) {
    if (blockIdx.x >= 402) {                          // ---- qp branch
        int t = blockIdx.x - 402;                     // 0..255
        int b = t >> 1;
        int d = (t & 1) * 256 + threadIdx.x;
        if (d >= DD) return;
        const float* qrow = query + (size_t)b * QQ;
        float acc = 0.f;
        #pragma unroll 8
        for (int q = 0; q < QQ; q++) acc += qrow[q] * attW[(size_t)q * DD + d];
        qp[(size_t)b * DD + d] = acc;
        return;
    }
    if (blockIdx.x >= 400) {
        int k = (blockIdx.x - 400) * 256 + threadIdx.x;
        if (k >= KP) return;
        float vs = 0.f, vd = 0.f;
        if (k < DD) {
            for (int j = 0; j < DD; j++) {
                float t = theta[j * DD + k];
                vs += t * att_src[j];
                vd += t * att_dst[j];
            }
        }
        int ks = k >> 5, kk = k & 31, q = kk >> 3, kb = kk & 7;
        size_t b0 = (size_t)ks * BPK_KS + DD * 32 + bswz(q, DD) * 8 + kb;
        size_t b1 = (size_t)ks * BPK_KS + (DD + 1) * 32 + bswz(q, DD + 1) * 8 + kb;
        unsigned int u, uh, ul;
        u  = __float_as_uint(vs);
        uh = (u + 0x8000u) & 0xffff0000u;
        ul = (__float_as_uint(vs - __uint_as_float(uh)) + 0x8000u) >> 16;
        bpk[b0]         = (unsigned short)(uh >> 16);
        bpk[b0 + 10240] = (unsigned short)ul;
        u  = __float_as_uint(vd);
        uh = (u + 0x8000u) & 0xffff0000u;
        ul = (__float_as_uint(vd - __uint_as_float(uh)) + 0x8000u) >> 16;
        bpk[b1]         = (unsigned short)(uh >> 16);
        bpk[b1 + 10240] = (unsigned short)ul;
        return;
    }
    int idx = blockIdx.x * 256 + threadIdx.x;
    if (idx >= KP * KP) return;
    int n = idx / KP, k = idx % KP;
    if (n == DD || n == DD + 1) return;
    float v = (n < DD && k < DD) ? theta[n * DD + k] : 0.f;
    unsigned int u  = __float_as_uint(v);
    unsigned int uh = (u + 0x8000u) & 0xffff0000u;    // round-half-up bf16
    float hf = __uint_as_float(uh);
    float lo = v - hf;
    unsigned int ul = (__float_as_uint(lo) + 0x8000u) >> 16;
    int ks = k >> 5, kk = k & 31, q = kk >> 3, kb = kk & 7;
    size_t base = (size_t)ks * BPK_KS + n * 32 + bswz(q, n) * 8 + kb;
    bpk[base]         = (unsigned short)(uh >> 16);
    bpk[base + 10240] = (unsigned short)ul;
}

// ---------------------------------------------------------------- split-bf16 MFMA GEMM
// Structure unchanged from R6 (verified); epilogue writes C as BF16 (Gb) —
// G is only consumed by the aggregate gather, bf16 halves that traffic.
__global__ __launch_bounds__(256) void k_mfma_gemm(const float* __restrict__ A, int lda,
                                                   const unsigned short* __restrict__ Bpk,
                                                   unsigned short* __restrict__ Gb,
                                                   float* __restrict__ a_s,
                                                   float* __restrict__ a_d, int M) {
    __shared__ __attribute__((aligned(16))) unsigned short Bs[2][BPK_KS]; // 80KB

    const int tid   = threadIdx.x;
    const int lane  = tid & 63;
    const int wave  = tid >> 6;         // 0..3
    const int q     = lane >> 4;        // 0..3
    const int mr    = lane & 15;
    const int m0    = blockIdx.x * 64;
    const int nbase = wave * 80;
    const int kvalid = (lda == GS) ? GS : DD;   // readable floats per A row

    f32x4 acc[4][5];
    #pragma unroll
    for (int i = 0; i < 4; i++)
        #pragma unroll
        for (int j = 0; j < 5; j++)
            acc[i][j] = (f32x4){0.f, 0.f, 0.f, 0.f};

    const float* arow[4];
    bool rok[4];
    #pragma unroll
    for (int mt = 0; mt < 4; mt++) {
        int row = m0 + mt * 16 + mr;
        rok[mt]  = row < M;
        arow[mt] = A + (size_t)(row < M ? row : 0) * lda;
    }

    const char* gB = (const char*)Bpk;

    auto loadA = [&](float (&f)[4][8], int ks) {
        const int k0c = ks * 32 + q * 8;
        #pragma unroll
        for (int mt = 0; mt < 4; mt++) {
            if (rok[mt] && (k0c + 8 <= kvalid)) {
                float4 v0 = *(const float4*)(arow[mt] + k0c);
                float4 v1 = *(const float4*)(arow[mt] + k0c + 4);
                f[mt][0]=v0.x; f[mt][1]=v0.y; f[mt][2]=v0.z; f[mt][3]=v0.w;
                f[mt][4]=v1.x; f[mt][5]=v1.y; f[mt][6]=v1.z; f[mt][7]=v1.w;
            } else {
                #pragma unroll
                for (int p = 0; p < 8; p += 2) {
                    int k = k0c + p;
                    float2 t = {0.f, 0.f};
                    if (rok[mt] && k < kvalid) t = *(const float2*)(arow[mt] + k);  // DD even
                    f[mt][p] = t.x; f[mt][p+1] = t.y;
                }
            }
        }
    };

    auto stageB = [&](int buf, int ks) {
        const char* gsrc = gB + (size_t)(ks * BPK_KS) * 2;
        #pragma unroll
        for (int j = 0; j < 10; j++) {
            int chunk = j * 4 + wave;                 // 0..39, wave-uniform base
            gload_lds16(gsrc + chunk * 1024 + lane * 16,
                        (char*)Bs[buf] + chunk * 1024);
        }
    };

    float fcur[4][8], fnext[4][8];

    loadA(fcur, 0);
    stageB(0, 0);
    __syncthreads();

    #pragma unroll
    for (int ks = 0; ks < KSTEPS; ks++) {
        if (ks + 1 < KSTEPS) {
            stageB((ks + 1) & 1, ks + 1);
            loadA(fnext, ks + 1);
        }

        short8 ah[4], al[4];
        #pragma unroll
        for (int mt = 0; mt < 4; mt++) {
            #pragma unroll
            for (int p = 0; p < 8; p++) {
                unsigned int u  = __float_as_uint(fcur[mt][p]);
                unsigned int uh = (u + 0x8000u) & 0xffff0000u;   // round-half-up bf16
                float l = fcur[mt][p] - __uint_as_float(uh);
                ah[mt][p] = (short)(uh >> 16);
                al[mt][p] = (short)((__float_as_uint(l) + 0x8000u) >> 16);
            }
        }

        const unsigned short* Bc = Bs[ks & 1];
        short8 bh[5], bl[5];
        #pragma unroll
        for (int nt = 0; nt < 5; nt++) {
            int col = nbase + nt * 16 + mr;
            int off = col * 32 + bswz(q, col) * 8;
            bh[nt] = *(const short8*)&Bc[off];
            bl[nt] = *(const short8*)&Bc[10240 + off];
        }
        #pragma unroll
        for (int nt = 0; nt < 5; nt++) {
            #pragma unroll
            for (int mt = 0; mt < 4; mt++) {
                acc[mt][nt] = __builtin_amdgcn_mfma_f32_16x16x32_bf16(ah[mt], bh[nt], acc[mt][nt], 0, 0, 0);
                acc[mt][nt] = __builtin_amdgcn_mfma_f32_16x16x32_bf16(ah[mt], bl[nt], acc[mt][nt], 0, 0, 0);
                acc[mt][nt] = __builtin_amdgcn_mfma_f32_16x16x32_bf16(al[mt], bh[nt], acc[mt][nt], 0, 0, 0);
            }
        }

        __syncthreads();

        #pragma unroll
        for (int mt = 0; mt < 4; mt++)
            #pragma unroll
            for (int p = 0; p < 8; p++)
                fcur[mt][p] = fnext[mt][p];
    }

    // epilogue: C/D layout col=lane&15, row=(lane>>4)*4+reg; bf16 store, pads zeroed
    #pragma unroll
    for (int mt = 0; mt < 4; mt++) {
        int row_b = m0 + mt * 16 + q * 4;
        #pragma unroll
        for (int nt = 0; nt < 5; nt++) {
            int col = nbase + nt * 16 + mr;
            if (col > DD + 1) continue;
            #pragma unroll
            for (int r = 0; r < 4; r++) {
                int row = row_b + r;
                if (row >= M) continue;
                float v = acc[mt][nt][r];
                if (col < DD) {
                    Gb[(size_t)row * GS + col] = f2bf(v);
                } else if (col == DD) {
                    a_s[row] = v;
                    Gb[(size_t)row * GS + DD] = 0;        // keep pad col zero
                } else {
                    a_d[row] = v;
                    Gb[(size_t)row * GS + DD + 1] = 0;    // keep pad col zero
                }
            }
        }
    }
}

// ---------------------------------------------------------------- tiled SGEMM (final linear)
#define BM 64
#define BN 64
#define BK 16
__global__ __launch_bounds__(256) void k_gemm_nt(const float* __restrict__ A,
                                                 const float* __restrict__ B,
                                                 float* __restrict__ C,
                                                 int M, int N, int K,
                                                 const float* __restrict__ bias,
                                                 int relu_a) {
    __shared__ float As[BK][BM + 4];
    __shared__ float Bs[BK][BN + 4];
    int m0 = blockIdx.y * BM;
    int n0 = blockIdx.x * BN;
    int tid = threadIdx.x;
    int tr = tid >> 4;
    int tc = tid & 15;
    float acc[4][4] = {};
    for (int k0 = 0; k0 < K; k0 += BK) {
        #pragma unroll
        for (int j = 0; j < 4; j++) {
            int e = tid + 256 * j;
            int r = e >> 4;
            int k = e & 15;
            int gk = k0 + k;
            int gm = m0 + r;
            float va = 0.f;
            if (gm < M && gk < K) va = A[(size_t)gm * K + gk];
            if (relu_a) va = fmaxf(va, 0.f);
            As[k][r] = va;
            int gn = n0 + r;
            float vb = 0.f;
            if (gn < N && gk < K) vb = B[(size_t)gn * K + gk];
            Bs[k][r] = vb;
        }
        __syncthreads();
        #pragma unroll
        for (int k = 0; k < BK; k++) {
            float a[4], b[4];
            #pragma unroll
            for (int i = 0; i < 4; i++) a[i] = As[k][tr * 4 + i];
            #pragma unroll
            for (int j = 0; j < 4; j++) b[j] = Bs[k][tc * 4 + j];
            #pragma unroll
            for (int i = 0; i < 4; i++)
                #pragma unroll
                for (int j = 0; j < 4; j++)
                    acc[i][j] += a[i] * b[j];
        }
        __syncthreads();
    }
    #pragma unroll
    for (int i = 0; i < 4; i++) {
        int gm = m0 + tr * 4 + i;
        if (gm >= M) continue;
        #pragma unroll
        for (int j = 0; j < 4; j++) {
            int gn = n0 + tc * 4 + j;
            if (gn < N) {
                float v = acc[i][j];
                if (bias) v += bias[gn];
                C[(size_t)gm * N + gn] = v;
            }
        }
    }
}

// ---------------------------------------------------------------- softmax-aggregate (wave / dst node)
// Online-softmax stats + bf16 gather (short8 = 16B/lane; lanes 0..37 cover the
// 608B row).  base = offs[n]+partials[n>>8]+n, cnt = deg[n]+1.
__global__ __launch_bounds__(256) void k_aggregate(const unsigned short* __restrict__ Gb,
                                                   const float* __restrict__ a_s,
                                                   const float* __restrict__ a_d,
                                                   const int* __restrict__ offs,
                                                   const int* __restrict__ partials,
                                                   const int* __restrict__ deg,
                                                   const int* __restrict__ esrc,
                                                   const float* __restrict__ bias,
                                                   float* __restrict__ out,
                                                   const float* __restrict__ qp,
                                                   const int* __restrict__ batch,
                                                   float* __restrict__ sarr) {
    int gid = blockIdx.x * blockDim.x + threadIdx.x;
    int n = gid >> 6, lane = gid & 63;
    if (n >= N_NODES) return;
    int beg = offs[n] + partials[n >> 8] + n;
    int cnt = deg[n] + 1;
    float adn = a_d[n];

    // ---- online softmax stats (one pass; finite sentinel avoids inf-inf NaN)
    float m = -1.0e30f, den = 0.f;
    for (int i = lane; i < cnt; i += 64) {
        float e = a_s[esrc[beg + i]] + adn;
        e = (e > 0.f) ? e : NEG_SLOPE * e;
        float nm = fmaxf(m, e);
        den = den * __expf(m - nm) + __expf(e - nm);
        m = nm;
    }
    for (int off = 32; off; off >>= 1) {
        float mo = __shfl_xor(m, off);
        float dn = __shfl_xor(den, off);
        float nm = fmaxf(m, mo);
        den = den * __expf(m - nm) + dn * __expf(mo - nm);
        m = nm;
    }
    float inv_den = 1.f / den;

    const int c0 = lane * 8;            // 8 bf16 cols per lane; lanes 0..37 active
    const bool act = c0 < GS;
    float A8[8] = {0.f,0.f,0.f,0.f,0.f,0.f,0.f,0.f};
    #pragma unroll 2
    for (int i = 0; i < cnt; i++) {
        int s = esrc[beg + i];
        float e = a_s[s] + adn;
        e = (e > 0.f) ? e : NEG_SLOPE * e;
        float w = __expf(e - m) * inv_den;
        if (act) {
            short8 v = *(const short8*)(Gb + (size_t)s * GS + c0);
            #pragma unroll
            for (int p = 0; p < 8; p++)
                A8[p] += w * bf2f((unsigned short)v[p]);
        }
    }

    // ---- bias + ReLU + write P (fp32); pads 302/303 -> 0
    float o[8];
    if (act) {
        #pragma unroll
        for (int p = 0; p < 8; p++) {
            int col = c0 + p;
            float b = (col < DD) ? bias[col] : 0.f;
            o[p] = (col < DD) ? fmaxf(A8[p] + b, 0.f) : 0.f;
        }
        float4 w0 = {o[0], o[1], o[2], o[3]};
        float4 w1 = {o[4], o[5], o[6], o[7]};
        *(float4*)(out + (size_t)n * GS + c0)     = w0;
        *(float4*)(out + (size_t)n * GS + c0 + 4) = w1;
    }

    // ---- fused pooling score (layer 3 only)
    if (sarr) {
        float d = 0.f;
        if (act) {
            const float* qv = qp + (size_t)batch[n] * DD;
            #pragma unroll
            for (int p = 0; p < 8; p++) {
                int col = c0 + p;
                if (col < DD) d += o[p] * qv[col];
            }
        }
        for (int off = 32; off; off >>= 1) d += __shfl_xor(d, off);
        if (lane == 0) sarr[n] = d * 0.04082482904638630f;   // 1/sqrt(600)
    }
}

// ---------------------------------------------------------------- pooling pieces
// per-graph softmax stats; fused: inline bounds search, writes wn, zeros pooled[b]
__global__ __launch_bounds__(256) void k_gstats(const float* __restrict__ sarr,
                                                const int* __restrict__ batch,
                                                float* __restrict__ wn,
                                                float* __restrict__ pooled) {
    int b = blockIdx.x;
    int lo = 0, hi = N_NODES;
    while (lo < hi) { int mid = (lo + hi) >> 1; if (batch[mid] < b) lo = mid + 1; else hi = mid; }
    int beg = lo;
    hi = N_NODES;
    while (lo < hi) { int mid = (lo + hi) >> 1; if (batch[mid] < b + 1) lo = mid + 1; else hi = mid; }
    int cnt = lo - beg;

    __shared__ float red[256];
    float m = -INFINITY;
    for (int i = threadIdx.x; i < cnt; i += 256) m = fmaxf(m, sarr[beg + i]);
    red[threadIdx.x] = m;
    __syncthreads();
    for (int d = 128; d; d >>= 1) {
        if (threadIdx.x < d) red[threadIdx.x] = fmaxf(red[threadIdx.x], red[threadIdx.x + d]);
        __syncthreads();
    }
    m = red[0];
    __syncthreads();
    float den = 0.f;
    for (int i = threadIdx.x; i < cnt; i += 256) den += __expf(sarr[beg + i] - m);
    red[threadIdx.x] = den;
    __syncthreads();
    for (int d = 128; d; d >>= 1) {
        if (threadIdx.x < d) red[threadIdx.x] += red[threadIdx.x + d];
        __syncthreads();
    }
    float dinv = (cnt > 0) ? 1.f / red[0] : 0.f;
    for (int i = threadIdx.x; i < cnt; i += 256)
        wn[beg + i] = __expf(sarr[beg + i] - m) * dinv;
    for (int j = threadIdx.x; j < DD; j += 256)
        pooled[(size_t)b * DD + j] = 0.f;
}

// node-chunk-parallel weighted segment sum (batch sorted; flush at graph boundaries)
__global__ __launch_bounds__(256) void k_poolacc(const float* __restrict__ h, int ld,
                                                 const float* __restrict__ wn,
                                                 const int* __restrict__ batch,
                                                 float* __restrict__ pooled) {
    int c0 = blockIdx.x * PC;
    if (c0 >= N_NODES) return;
    int nmax = N_NODES - c0; if (nmax > PC) nmax = PC;
    __shared__ int   sb[PC];
    __shared__ float sw[PC];
    for (int i = threadIdx.x; i < nmax; i += 256) {
        sb[i] = batch[c0 + i];
        sw[i] = wn[c0 + i];
    }
    __syncthreads();
    int f0 = threadIdx.x, f1 = threadIdx.x + 256;
    float a0 = 0.f, a1 = 0.f;
    int g = sb[0];
    for (int i = 0; i < nmax; i++) {
        int bi = sb[i];
        if (bi != g) {                       // wave-uniform branch
            if (f0 < DD) atomicAdd(&pooled[(size_t)g * DD + f0], a0);
            if (f1 < DD) atomicAdd(&pooled[(size_t)g * DD + f1], a1);
            a0 = 0.f; a1 = 0.f; g = bi;
        }
        float w = sw[i];
        const float* row = h + (size_t)(c0 + i) * ld;
        if (f0 < DD) a0 += w * row[f0];
        if (f1 < DD) a1 += w * row[f1];
    }
    if (f0 < DD) atomicAdd(&pooled[(size_t)g * DD + f0], a0);
    if (f1 < DD) atomicAdd(&pooled[(size_t)g * DD + f1], a1);
}

// ---------------------------------------------------------------- launch
extern "C" void kernel_launch(void* const* d_in, const int* in_sizes, int n_in,
                              void* d_out, int out_size, void* d_ws, size_t ws_size,
                              hipStream_t stream) {
    const float* x        = (const float*)d_in[0];
    const int*   edges    = (const int*)d_in[1];   // [2, E]
    const float* query    = (const float*)d_in[2];
    const int*   batch    = (const int*)d_in[3];
    const float* theta    = (const float*)d_in[4];
    const float* att_src  = (const float*)d_in[5];
    const float* att_dst  = (const float*)d_in[6];
    const float* gat_bias = (const float*)d_in[7];
    const float* attW     = (const float*)d_in[8];
    const float* lin_w    = (const float*)d_in[9];
    const float* lin_b    = (const float*)d_in[10];
    float* out = (float*)d_out;

    char* ws = (char*)d_ws;
    size_t off = 0;
    auto alloc = [&](size_t bytes) -> void* {
        off = (off + 255) & ~(size_t)255;
        void* p = ws + off;
        off += bytes;
        return p;
    };

    unsigned short* Gb = (unsigned short*)alloc((size_t)N_NODES * GS * 2);  // gemm output (bf16)
    float* P    = (float*)alloc((size_t)N_NODES * GS * 4);   // layer output (padded stride)
    unsigned short* bpk = (unsigned short*)alloc((size_t)KSTEPS * BPK_KS * 2); // packed B, 409.6KB
    float* a_s  = (float*)alloc((size_t)N_NODES * 4);
    float* a_d  = (float*)alloc((size_t)N_NODES * 4);
    float* sarr = (float*)alloc((size_t)N_NODES * 4);
    float* wn   = (float*)alloc((size_t)N_NODES * 4);
    int* deg    = (int*)alloc((size_t)N_NODES * 4);
    int* cursor = (int*)alloc((size_t)N_NODES * 4);
    int* offs   = (int*)alloc((size_t)N_NODES * 4);
    int* esrc   = (int*)alloc((size_t)(N_EDGES + N_NODES) * 4);
    int* partials = (int*)alloc(256 * 4);
    float* qp   = (float*)alloc((size_t)BB * DD * 4);
    float* pooled = (float*)alloc((size_t)BB * DD * 4);

    const int* e_src = edges;
    const int* e_dst = edges + N_EDGES;

    const int NB_SCAN = (N_NODES + 255) / 256;   // 196

    // ---- CSR build (deg/cursor zeroed via kernel; self-loop slot implicit)
    k_zero_dc<<<NB_SCAN, 256, 0, stream>>>(deg, cursor);
    k_histogram<<<(N_EDGES + 255) / 256, 256, 0, stream>>>(e_dst, deg);
    k_scan_block<<<NB_SCAN, 256, 0, stream>>>(deg, offs, partials);
    k_scan_partials<<<1, 256, 0, stream>>>(partials, NB_SCAN);
    k_scatter<<<(N_EDGES + N_NODES + 255) / 256, 256, 0, stream>>>(e_src, e_dst, offs, partials, deg, cursor, esrc);

    // ---- theta hi/lo split + attvec rows + qp (one fused dispatch)
    k_theta_qp<<<658, 256, 0, stream>>>(theta, att_src, att_dst, bpk, query, attW, qp);

    // ---- 3 GAT layers (layer 3 fuses pooling scores)
    int mfma_blocks = (N_NODES + 63) / 64;   // 782
    int wave_blocks = (N_NODES + 3) / 4;
    const float* cur = x;
    int cur_ld = DD;
    for (int layer = 0; layer < 3; layer++) {
        k_mfma_gemm<<<mfma_blocks, 256, 0, stream>>>(cur, cur_ld, bpk, Gb, a_s, a_d, N_NODES);
        bool last = (layer == 2);
        k_aggregate<<<wave_blocks, 256, 0, stream>>>(Gb, a_s, a_d, offs, partials, deg, esrc, gat_bias, P,
                                                     last ? qp : (const float*)nullptr,
                                                     last ? batch : (const int*)nullptr,
                                                     last ? sarr : (float*)nullptr);
        cur = P;
        cur_ld = GS;
    }

    // ---- attention pooling + classifier
    k_gstats<<<BB, 256, 0, stream>>>(sarr, batch, wn, pooled);
    k_poolacc<<<(N_NODES + PC - 1) / PC, 256, 0, stream>>>(P, GS, wn, batch, pooled);
    {
        dim3 g((CC + BN - 1) / BN, (BB + BM - 1) / BM);
        k_gemm_nt<<<g, 256, 0, stream>>>(pooled, lin_w, out, BB, CC, DD, lin_b, 1);
    }
}

// Round 10
// 646.691 us; speedup vs baseline: 1.2159x; 1.0784x over previous
//
#include <hip/hip_runtime.h>
#include <hip/hip_bf16.h>
#include <math.h>

#define N_NODES 50000
#define N_EDGES 250000
#define BB      128
#define DD      302
#define QQ      600
#define CC      2000
#define NEG_SLOPE 0.2f
#define GS      304        // padded row stride for G and P (16B-aligned rows)
#define KP      320        // padded K (10 x 32)
#define KSTEPS  10         // KP / 32
#define PC      64         // nodes per pooling chunk
#define BPK_KS  20480      // shorts per k-step in packed B: [hi 320x32][lo 320x32]

typedef __attribute__((ext_vector_type(8))) short short8;
typedef __attribute__((ext_vector_type(4))) float f32x4;

__device__ __forceinline__ void gload_lds16(const void* g, void* l) {
    __builtin_amdgcn_global_load_lds((const __attribute__((address_space(1))) void*)g,
                                     (__attribute__((address_space(3))) void*)l, 16, 0, 0);
}

// bank-spread slot for packed B: 2 lanes/bank on ds_read_b128 (free per m136)
__device__ __host__ __forceinline__ int bswz(int q, int n) {
    return q ^ (n & 3) ^ ((n >> 2) & 3);
}

__device__ __forceinline__ unsigned short f2bf(float v) {   // round-half-up bf16
    return (unsigned short)((__float_as_uint(v) + 0x8000u) >> 16);
}

// ---------------------------------------------------------------- CSR build
// deg = pure in-edge histogram; self-loop slot is implicit:
// node n owns esrc slots [offs[n]+partials[n>>8]+n, ... + deg[n]] (deg[n]+1 slots).
__global__ void k_zero_dc(int* deg, int* cursor) {
    int i = blockIdx.x * 256 + threadIdx.x;
    if (i < N_NODES) { deg[i] = 0; cursor[i] = 0; }
}

__global__ void k_histogram(const int* __restrict__ dst, int* deg) {
    int e = blockIdx.x * blockDim.x + threadIdx.x;
    if (e < N_EDGES) atomicAdd(&deg[dst[e]], 1);
}

__global__ void k_scan_block(const int* __restrict__ deg, int* offs, int* partials) {
    __shared__ int sh[256];
    int i = blockIdx.x * 256 + threadIdx.x;
    int v = (i < N_NODES) ? deg[i] : 0;
    sh[threadIdx.x] = v;
    __syncthreads();
    for (int d = 1; d < 256; d <<= 1) {
        int t = (threadIdx.x >= d) ? sh[threadIdx.x - d] : 0;
        __syncthreads();
        sh[threadIdx.x] += t;
        __syncthreads();
    }
    if (i < N_NODES) offs[i] = sh[threadIdx.x] - v;   // exclusive (block-local)
    if (threadIdx.x == 255) partials[blockIdx.x] = sh[255];
}

__global__ void k_scan_partials(int* partials, int nb) {
    __shared__ int sh[256];
    int v = (threadIdx.x < nb) ? partials[threadIdx.x] : 0;
    sh[threadIdx.x] = v;
    __syncthreads();
    for (int d = 1; d < 256; d <<= 1) {
        int t = (threadIdx.x >= d) ? sh[threadIdx.x - d] : 0;
        __syncthreads();
        sh[threadIdx.x] += t;
        __syncthreads();
    }
    if (threadIdx.x < nb) partials[threadIdx.x] = sh[threadIdx.x] - v;  // exclusive
}

__global__ void k_scatter(const int* __restrict__ src, const int* __restrict__ dst,
                          const int* __restrict__ offs, const int* __restrict__ partials,
                          const int* __restrict__ deg, int* cursor, int* esrc) {
    int i = blockIdx.x * blockDim.x + threadIdx.x;
    if (i < N_EDGES) {
        int d = dst[i];
        int base = offs[d] + partials[d >> 8] + d;
        int pos = base + atomicAdd(&cursor[d], 1);
        esrc[pos] = src[i];
    } else if (i < N_EDGES + N_NODES) {
        int n = i - N_EDGES;
        int base = offs[n] + partials[n >> 8] + n;
        esrc[base + deg[n]] = n;   // self loop in the last slot (deg final before this kernel)
    }
}

// ---------------------------------------------------------------- theta pack + attvec rows + qp (one dispatch)
__global__ void k_theta_qp(const float* __restrict__ theta,
                           const float* __restrict__ att_src,
                           const float* __restrict__ att_dst,
                           unsigned short* __restrict__ bpk,
                           const float* __restrict__ query,
                           const float* __restrict__ attW,
                           float* __restrict__ qp) {
    if (blockIdx.x >= 402) {                          // ---- qp branch
        int t = blockIdx.x - 402;                     // 0..255
        int b = t >> 1;
        int d = (t & 1) * 256 + threadIdx.x;
        if (d >= DD) return;
        const float* qrow = query + (size_t)b * QQ;
        float acc = 0.f;
        #pragma unroll 8
        for (int q = 0; q < QQ; q++) acc += qrow[q] * attW[(size_t)q * DD + d];
        qp[(size_t)b * DD + d] = acc;
        return;
    }
    if (blockIdx.x >= 400) {
        int k = (blockIdx.x - 400) * 256 + threadIdx.x;
        if (k >= KP) return;
        float vs = 0.f, vd = 0.f;
        if (k < DD) {
            for (int j = 0; j < DD; j++) {
                float t = theta[j * DD + k];
                vs += t * att_src[j];
                vd += t * att_dst[j];
            }
        }
        int ks = k >> 5, kk = k & 31, q = kk >> 3, kb = kk & 7;
        size_t b0 = (size_t)ks * BPK_KS + DD * 32 + bswz(q, DD) * 8 + kb;
        size_t b1 = (size_t)ks * BPK_KS + (DD + 1) * 32 + bswz(q, DD + 1) * 8 + kb;
        unsigned int u, uh, ul;
        u  = __float_as_uint(vs);
        uh = (u + 0x8000u) & 0xffff0000u;
        ul = (__float_as_uint(vs - __uint_as_float(uh)) + 0x8000u) >> 16;
        bpk[b0]         = (unsigned short)(uh >> 16);
        bpk[b0 + 10240] = (unsigned short)ul;
        u  = __float_as_uint(vd);
        uh = (u + 0x8000u) & 0xffff0000u;
        ul = (__float_as_uint(vd - __uint_as_float(uh)) + 0x8000u) >> 16;
        bpk[b1]         = (unsigned short)(uh >> 16);
        bpk[b1 + 10240] = (unsigned short)ul;
        return;
    }
    int idx = blockIdx.x * 256 + threadIdx.x;
    if (idx >= KP * KP) return;
    int n = idx / KP, k = idx % KP;
    if (n == DD || n == DD + 1) return;
    float v = (n < DD && k < DD) ? theta[n * DD + k] : 0.f;
    unsigned int u  = __float_as_uint(v);
    unsigned int uh = (u + 0x8000u) & 0xffff0000u;    // round-half-up bf16
    float hf = __uint_as_float(uh);
    float lo = v - hf;
    unsigned int ul = (__float_as_uint(lo) + 0x8000u) >> 16;
    int ks = k >> 5, kk = k & 31, q = kk >> 3, kb = kk & 7;
    size_t base = (size_t)ks * BPK_KS + n * 32 + bswz(q, n) * 8 + kb;
    bpk[base]         = (unsigned short)(uh >> 16);
    bpk[base + 10240] = (unsigned short)ul;
}

// ---------------------------------------------------------------- split-bf16 MFMA GEMM
// Structure unchanged from R6 (verified); epilogue writes C as BF16 (Gb).
__global__ __launch_bounds__(256) void k_mfma_gemm(const float* __restrict__ A, int lda,
                                                   const unsigned short* __restrict__ Bpk,
                                                   unsigned short* __restrict__ Gb,
                                                   float* __restrict__ a_s,
                                                   float* __restrict__ a_d, int M) {
    __shared__ __attribute__((aligned(16))) unsigned short Bs[2][BPK_KS]; // 80KB

    const int tid   = threadIdx.x;
    const int lane  = tid & 63;
    const int wave  = tid >> 6;         // 0..3
    const int q     = lane >> 4;        // 0..3
    const int mr    = lane & 15;
    const int m0    = blockIdx.x * 64;
    const int nbase = wave * 80;
    const int kvalid = (lda == GS) ? GS : DD;   // readable floats per A row

    f32x4 acc[4][5];
    #pragma unroll
    for (int i = 0; i < 4; i++)
        #pragma unroll
        for (int j = 0; j < 5; j++)
            acc[i][j] = (f32x4){0.f, 0.f, 0.f, 0.f};

    const float* arow[4];
    bool rok[4];
    #pragma unroll
    for (int mt = 0; mt < 4; mt++) {
        int row = m0 + mt * 16 + mr;
        rok[mt]  = row < M;
        arow[mt] = A + (size_t)(row < M ? row : 0) * lda;
    }

    const char* gB = (const char*)Bpk;

    auto loadA = [&](float (&f)[4][8], int ks) {
        const int k0c = ks * 32 + q * 8;
        #pragma unroll
        for (int mt = 0; mt < 4; mt++) {
            if (rok[mt] && (k0c + 8 <= kvalid)) {
                float4 v0 = *(const float4*)(arow[mt] + k0c);
                float4 v1 = *(const float4*)(arow[mt] + k0c + 4);
                f[mt][0]=v0.x; f[mt][1]=v0.y; f[mt][2]=v0.z; f[mt][3]=v0.w;
                f[mt][4]=v1.x; f[mt][5]=v1.y; f[mt][6]=v1.z; f[mt][7]=v1.w;
            } else {
                #pragma unroll
                for (int p = 0; p < 8; p += 2) {
                    int k = k0c + p;
                    float2 t = {0.f, 0.f};
                    if (rok[mt] && k < kvalid) t = *(const float2*)(arow[mt] + k);  // DD even
                    f[mt][p] = t.x; f[mt][p+1] = t.y;
                }
            }
        }
    };

    auto stageB = [&](int buf, int ks) {
        const char* gsrc = gB + (size_t)(ks * BPK_KS) * 2;
        #pragma unroll
        for (int j = 0; j < 10; j++) {
            int chunk = j * 4 + wave;                 // 0..39, wave-uniform base
            gload_lds16(gsrc + chunk * 1024 + lane * 16,
                        (char*)Bs[buf] + chunk * 1024);
        }
    };

    float fcur[4][8], fnext[4][8];

    loadA(fcur, 0);
    stageB(0, 0);
    __syncthreads();

    #pragma unroll
    for (int ks = 0; ks < KSTEPS; ks++) {
        if (ks + 1 < KSTEPS) {
            stageB((ks + 1) & 1, ks + 1);
            loadA(fnext, ks + 1);
        }

        short8 ah[4], al[4];
        #pragma unroll
        for (int mt = 0; mt < 4; mt++) {
            #pragma unroll
            for (int p = 0; p < 8; p++) {
                unsigned int u  = __float_as_uint(fcur[mt][p]);
                unsigned int uh = (u + 0x8000u) & 0xffff0000u;   // round-half-up bf16
                float l = fcur[mt][p] - __uint_as_float(uh);
                ah[mt][p] = (short)(uh >> 16);
                al[mt][p] = (short)((__float_as_uint(l) + 0x8000u) >> 16);
            }
        }

        const unsigned short* Bc = Bs[ks & 1];
        short8 bh[5], bl[5];
        #pragma unroll
        for (int nt = 0; nt < 5; nt++) {
            int col = nbase + nt * 16 + mr;
            int off = col * 32 + bswz(q, col) * 8;
            bh[nt] = *(const short8*)&Bc[off];
            bl[nt] = *(const short8*)&Bc[10240 + off];
        }
        #pragma unroll
        for (int nt = 0; nt < 5; nt++) {
            #pragma unroll
            for (int mt = 0; mt < 4; mt++) {
                acc[mt][nt] = __builtin_amdgcn_mfma_f32_16x16x32_bf16(ah[mt], bh[nt], acc[mt][nt], 0, 0, 0);
                acc[mt][nt] = __builtin_amdgcn_mfma_f32_16x16x32_bf16(ah[mt], bl[nt], acc[mt][nt], 0, 0, 0);
                acc[mt][nt] = __builtin_amdgcn_mfma_f32_16x16x32_bf16(al[mt], bh[nt], acc[mt][nt], 0, 0, 0);
            }
        }

        __syncthreads();

        #pragma unroll
        for (int mt = 0; mt < 4; mt++)
            #pragma unroll
            for (int p = 0; p < 8; p++)
                fcur[mt][p] = fnext[mt][p];
    }

    // epilogue: C/D layout col=lane&15, row=(lane>>4)*4+reg; bf16 store, pads zeroed
    #pragma unroll
    for (int mt = 0; mt < 4; mt++) {
        int row_b = m0 + mt * 16 + q * 4;
        #pragma unroll
        for (int nt = 0; nt < 5; nt++) {
            int col = nbase + nt * 16 + mr;
            if (col > DD + 1) continue;
            #pragma unroll
            for (int r = 0; r < 4; r++) {
                int row = row_b + r;
                if (row >= M) continue;
                float v = acc[mt][nt][r];
                if (col < DD) {
                    Gb[(size_t)row * GS + col] = f2bf(v);
                } else if (col == DD) {
                    a_s[row] = v;
                    Gb[(size_t)row * GS + DD] = 0;        // keep pad col zero
                } else {
                    a_d[row] = v;
                    Gb[(size_t)row * GS + DD + 1] = 0;    // keep pad col zero
                }
            }
        }
    }
}

// ---------------------------------------------------------------- tiled SGEMM (final linear)
#define BM 64
#define BN 64
#define BK 16
__global__ __launch_bounds__(256) void k_gemm_nt(const float* __restrict__ A,
                                                 const float* __restrict__ B,
                                                 float* __restrict__ C,
                                                 int M, int N, int K,
                                                 const float* __restrict__ bias,
                                                 int relu_a) {
    __shared__ float As[BK][BM + 4];
    __shared__ float Bs[BK][BN + 4];
    int m0 = blockIdx.y * BM;
    int n0 = blockIdx.x * BN;
    int tid = threadIdx.x;
    int tr = tid >> 4;
    int tc = tid & 15;
    float acc[4][4] = {};
    for (int k0 = 0; k0 < K; k0 += BK) {
        #pragma unroll
        for (int j = 0; j < 4; j++) {
            int e = tid + 256 * j;
            int r = e >> 4;
            int k = e & 15;
            int gk = k0 + k;
            int gm = m0 + r;
            float va = 0.f;
            if (gm < M && gk < K) va = A[(size_t)gm * K + gk];
            if (relu_a) va = fmaxf(va, 0.f);
            As[k][r] = va;
            int gn = n0 + r;
            float vb = 0.f;
            if (gn < N && gk < K) vb = B[(size_t)gn * K + gk];
            Bs[k][r] = vb;
        }
        __syncthreads();
        #pragma unroll
        for (int k = 0; k < BK; k++) {
            float a[4], b[4];
            #pragma unroll
            for (int i = 0; i < 4; i++) a[i] = As[k][tr * 4 + i];
            #pragma unroll
            for (int j = 0; j < 4; j++) b[j] = Bs[k][tc * 4 + j];
            #pragma unroll
            for (int i = 0; i < 4; i++)
                #pragma unroll
                for (int j = 0; j < 4; j++)
                    acc[i][j] += a[i] * b[j];
        }
        __syncthreads();
    }
    #pragma unroll
    for (int i = 0; i < 4; i++) {
        int gm = m0 + tr * 4 + i;
        if (gm >= M) continue;
        #pragma unroll
        for (int j = 0; j < 4; j++) {
            int gn = n0 + tc * 4 + j;
            if (gn < N) {
                float v = acc[i][j];
                if (bias) v += bias[gn];
                C[(size_t)gm * N + gn] = v;
            }
        }
    }
}

// ---------------------------------------------------------------- softmax-aggregate (wave / dst node)
// Lane-parallel edge precompute: lane i loads esrc/a_s for edge i (PARALLEL),
// stats reduced via butterfly; gather loop gets (s, w) via __shfl (register-only,
// no dependent random loads) -> row loads are independent, unroll 4 deep.
// Edges >= 64 per node (vanishingly rare at E[deg]=6) use a serial fallback.
__global__ __launch_bounds__(256) void k_aggregate(const unsigned short* __restrict__ Gb,
                                                   const float* __restrict__ a_s,
                                                   const float* __restrict__ a_d,
                                                   const int* __restrict__ offs,
                                                   const int* __restrict__ partials,
                                                   const int* __restrict__ deg,
                                                   const int* __restrict__ esrc,
                                                   const float* __restrict__ bias,
                                                   float* __restrict__ out,
                                                   const float* __restrict__ qp,
                                                   const int* __restrict__ batch,
                                                   float* __restrict__ sarr) {
    int gid = blockIdx.x * blockDim.x + threadIdx.x;
    int n = gid >> 6, lane = gid & 63;
    if (n >= N_NODES) return;
    int beg = offs[n] + partials[n >> 8] + n;
    int cnt = deg[n] + 1;
    float adn = a_d[n];

    // ---- lane-parallel first chunk: lane i owns edge i
    int   s_reg = 0;
    float e_reg = -1.0e30f;
    float m = -1.0e30f, den = 0.f;
    if (lane < cnt) {
        s_reg = esrc[beg + lane];
        float e = a_s[s_reg] + adn;
        e = (e > 0.f) ? e : NEG_SLOPE * e;
        e_reg = e;
        m = e; den = 1.f;                 // exp(e-e)=1
    }
    // rare extra chunks: online accumulate
    for (int i = 64 + lane; i < cnt; i += 64) {
        float e = a_s[esrc[beg + i]] + adn;
        e = (e > 0.f) ? e : NEG_SLOPE * e;
        float nm = fmaxf(m, e);
        den = den * __expf(m - nm) + __expf(e - nm);
        m = nm;
    }
    // butterfly combine (finite sentinel keeps exp args finite)
    for (int off = 32; off; off >>= 1) {
        float mo = __shfl_xor(m, off);
        float dn = __shfl_xor(den, off);
        float nm = fmaxf(m, mo);
        den = den * __expf(m - nm) + dn * __expf(mo - nm);
        m = nm;
    }
    float inv_den = 1.f / den;
    float w_reg = __expf(e_reg - m) * inv_den;   // valid for lane < min(cnt,64)

    const int c0 = lane * 8;            // 8 bf16 cols per lane; lanes 0..37 active
    const bool act = c0 < GS;
    float A8[8] = {0.f,0.f,0.f,0.f,0.f,0.f,0.f,0.f};
    const int nfirst = (cnt < 64) ? cnt : 64;
    #pragma unroll 4
    for (int j = 0; j < nfirst; j++) {
        int   s = __shfl(s_reg, j);      // register broadcast — no memory dep
        float w = __shfl(w_reg, j);
        if (act) {
            int4 v = *(const int4*)(Gb + (size_t)s * GS + c0);
            unsigned int u0 = (unsigned int)v.x, u1 = (unsigned int)v.y;
            unsigned int u2 = (unsigned int)v.z, u3 = (unsigned int)v.w;
            A8[0] += w * __uint_as_float(u0 << 16);
            A8[1] += w * __uint_as_float(u0 & 0xffff0000u);
            A8[2] += w * __uint_as_float(u1 << 16);
            A8[3] += w * __uint_as_float(u1 & 0xffff0000u);
            A8[4] += w * __uint_as_float(u2 << 16);
            A8[5] += w * __uint_as_float(u2 & 0xffff0000u);
            A8[6] += w * __uint_as_float(u3 << 16);
            A8[7] += w * __uint_as_float(u3 & 0xffff0000u);
        }
    }
    // rare overflow edges: serial recompute path
    for (int i = 64; i < cnt; i++) {
        int s = esrc[beg + i];
        float e = a_s[s] + adn;
        e = (e > 0.f) ? e : NEG_SLOPE * e;
        float w = __expf(e - m) * inv_den;
        if (act) {
            int4 v = *(const int4*)(Gb + (size_t)s * GS + c0);
            unsigned int u0 = (unsigned int)v.x, u1 = (unsigned int)v.y;
            unsigned int u2 = (unsigned int)v.z, u3 = (unsigned int)v.w;
            A8[0] += w * __uint_as_float(u0 << 16);
            A8[1] += w * __uint_as_float(u0 & 0xffff0000u);
            A8[2] += w * __uint_as_float(u1 << 16);
            A8[3] += w * __uint_as_float(u1 & 0xffff0000u);
            A8[4] += w * __uint_as_float(u2 << 16);
            A8[5] += w * __uint_as_float(u2 & 0xffff0000u);
            A8[6] += w * __uint_as_float(u3 << 16);
            A8[7] += w * __uint_as_float(u3 & 0xffff0000u);
        }
    }

    // ---- bias + ReLU + write P (fp32); pads 302/303 -> 0
    float o[8];
    if (act) {
        #pragma unroll
        for (int p = 0; p < 8; p++) {
            int col = c0 + p;
            float b = (col < DD) ? bias[col] : 0.f;
            o[p] = (col < DD) ? fmaxf(A8[p] + b, 0.f) : 0.f;
        }
        float4 w0 = {o[0], o[1], o[2], o[3]};
        float4 w1 = {o[4], o[5], o[6], o[7]};
        *(float4*)(out + (size_t)n * GS + c0)     = w0;
        *(float4*)(out + (size_t)n * GS + c0 + 4) = w1;
    }

    // ---- fused pooling score (layer 3 only)
    if (sarr) {
        float d = 0.f;
        if (act) {
            const float* qv = qp + (size_t)batch[n] * DD;
            #pragma unroll
            for (int p = 0; p < 8; p++) {
                int col = c0 + p;
                if (col < DD) d += o[p] * qv[col];
            }
        }
        for (int off = 32; off; off >>= 1) d += __shfl_xor(d, off);
        if (lane == 0) sarr[n] = d * 0.04082482904638630f;   // 1/sqrt(600)
    }
}

// ---------------------------------------------------------------- pooling pieces
// per-graph softmax stats; fused: inline bounds search, writes wn, zeros pooled[b]
__global__ __launch_bounds__(256) void k_gstats(const float* __restrict__ sarr,
                                                const int* __restrict__ batch,
                                                float* __restrict__ wn,
                                                float* __restrict__ pooled) {
    int b = blockIdx.x;
    int lo = 0, hi = N_NODES;
    while (lo < hi) { int mid = (lo + hi) >> 1; if (batch[mid] < b) lo = mid + 1; else hi = mid; }
    int beg = lo;
    hi = N_NODES;
    while (lo < hi) { int mid = (lo + hi) >> 1; if (batch[mid] < b + 1) lo = mid + 1; else hi = mid; }
    int cnt = lo - beg;

    __shared__ float red[256];
    float m = -INFINITY;
    for (int i = threadIdx.x; i < cnt; i += 256) m = fmaxf(m, sarr[beg + i]);
    red[threadIdx.x] = m;
    __syncthreads();
    for (int d = 128; d; d >>= 1) {
        if (threadIdx.x < d) red[threadIdx.x] = fmaxf(red[threadIdx.x], red[threadIdx.x + d]);
        __syncthreads();
    }
    m = red[0];
    __syncthreads();
    float den = 0.f;
    for (int i = threadIdx.x; i < cnt; i += 256) den += __expf(sarr[beg + i] - m);
    red[threadIdx.x] = den;
    __syncthreads();
    for (int d = 128; d; d >>= 1) {
        if (threadIdx.x < d) red[threadIdx.x] += red[threadIdx.x + d];
        __syncthreads();
    }
    float dinv = (cnt > 0) ? 1.f / red[0] : 0.f;
    for (int i = threadIdx.x; i < cnt; i += 256)
        wn[beg + i] = __expf(sarr[beg + i] - m) * dinv;
    for (int j = threadIdx.x; j < DD; j += 256)
        pooled[(size_t)b * DD + j] = 0.f;
}

// node-chunk-parallel weighted segment sum (batch sorted; flush at graph boundaries)
__global__ __launch_bounds__(256) void k_poolacc(const float* __restrict__ h, int ld,
                                                 const float* __restrict__ wn,
                                                 const int* __restrict__ batch,
                                                 float* __restrict__ pooled) {
    int c0 = blockIdx.x * PC;
    if (c0 >= N_NODES) return;
    int nmax = N_NODES - c0; if (nmax > PC) nmax = PC;
    __shared__ int   sb[PC];
    __shared__ float sw[PC];
    for (int i = threadIdx.x; i < nmax; i += 256) {
        sb[i] = batch[c0 + i];
        sw[i] = wn[c0 + i];
    }
    __syncthreads();
    int f0 = threadIdx.x, f1 = threadIdx.x + 256;
    float a0 = 0.f, a1 = 0.f;
    int g = sb[0];
    for (int i = 0; i < nmax; i++) {
        int bi = sb[i];
        if (bi != g) {                       // wave-uniform branch
            if (f0 < DD) atomicAdd(&pooled[(size_t)g * DD + f0], a0);
            if (f1 < DD) atomicAdd(&pooled[(size_t)g * DD + f1], a1);
            a0 = 0.f; a1 = 0.f; g = bi;
        }
        float w = sw[i];
        const float* row = h + (size_t)(c0 + i) * ld;
        if (f0 < DD) a0 += w * row[f0];
        if (f1 < DD) a1 += w * row[f1];
    }
    if (f0 < DD) atomicAdd(&pooled[(size_t)g * DD + f0], a0);
    if (f1 < DD) atomicAdd(&pooled[(size_t)g * DD + f1], a1);
}

// ---------------------------------------------------------------- launch
extern "C" void kernel_launch(void* const* d_in, const int* in_sizes, int n_in,
                              void* d_out, int out_size, void* d_ws, size_t ws_size,
                              hipStream_t stream) {
    const float* x        = (const float*)d_in[0];
    const int*   edges    = (const int*)d_in[1];   // [2, E]
    const float* query    = (const float*)d_in[2];
    const int*   batch    = (const int*)d_in[3];
    const float* theta    = (const float*)d_in[4];
    const float* att_src  = (const float*)d_in[5];
    const float* att_dst  = (const float*)d_in[6];
    const float* gat_bias = (const float*)d_in[7];
    const float* attW     = (const float*)d_in[8];
    const float* lin_w    = (const float*)d_in[9];
    const float* lin_b    = (const float*)d_in[10];
    float* out = (float*)d_out;

    char* ws = (char*)d_ws;
    size_t off = 0;
    auto alloc = [&](size_t bytes) -> void* {
        off = (off + 255) & ~(size_t)255;
        void* p = ws + off;
        off += bytes;
        return p;
    };

    unsigned short* Gb = (unsigned short*)alloc((size_t)N_NODES * GS * 2);  // gemm output (bf16)
    float* P    = (float*)alloc((size_t)N_NODES * GS * 4);   // layer output (padded stride)
    unsigned short* bpk = (unsigned short*)alloc((size_t)KSTEPS * BPK_KS * 2); // packed B, 409.6KB
    float* a_s  = (float*)alloc((size_t)N_NODES * 4);
    float* a_d  = (float*)alloc((size_t)N_NODES * 4);
    float* sarr = (float*)alloc((size_t)N_NODES * 4);
    float* wn   = (float*)alloc((size_t)N_NODES * 4);
    int* deg    = (int*)alloc((size_t)N_NODES * 4);
    int* cursor = (int*)alloc((size_t)N_NODES * 4);
    int* offs   = (int*)alloc((size_t)N_NODES * 4);
    int* esrc   = (int*)alloc((size_t)(N_EDGES + N_NODES) * 4);
    int* partials = (int*)alloc(256 * 4);
    float* qp   = (float*)alloc((size_t)BB * DD * 4);
    float* pooled = (float*)alloc((size_t)BB * DD * 4);

    const int* e_src = edges;
    const int* e_dst = edges + N_EDGES;

    const int NB_SCAN = (N_NODES + 255) / 256;   // 196

    // ---- CSR build (deg/cursor zeroed via kernel; self-loop slot implicit)
    k_zero_dc<<<NB_SCAN, 256, 0, stream>>>(deg, cursor);
    k_histogram<<<(N_EDGES + 255) / 256, 256, 0, stream>>>(e_dst, deg);
    k_scan_block<<<NB_SCAN, 256, 0, stream>>>(deg, offs, partials);
    k_scan_partials<<<1, 256, 0, stream>>>(partials, NB_SCAN);
    k_scatter<<<(N_EDGES + N_NODES + 255) / 256, 256, 0, stream>>>(e_src, e_dst, offs, partials, deg, cursor, esrc);

    // ---- theta hi/lo split + attvec rows + qp (one fused dispatch)
    k_theta_qp<<<658, 256, 0, stream>>>(theta, att_src, att_dst, bpk, query, attW, qp);

    // ---- 3 GAT layers (layer 3 fuses pooling scores)
    int mfma_blocks = (N_NODES + 63) / 64;   // 782
    int wave_blocks = (N_NODES + 3) / 4;
    const float* cur = x;
    int cur_ld = DD;
    for (int layer = 0; layer < 3; layer++) {
        k_mfma_gemm<<<mfma_blocks, 256, 0, stream>>>(cur, cur_ld, bpk, Gb, a_s, a_d, N_NODES);
        bool last = (layer == 2);
        k_aggregate<<<wave_blocks, 256, 0, stream>>>(Gb, a_s, a_d, offs, partials, deg, esrc, gat_bias, P,
                                                     last ? qp : (const float*)nullptr,
                                                     last ? batch : (const int*)nullptr,
                                                     last ? sarr : (float*)nullptr);
        cur = P;
        cur_ld = GS;
    }

    // ---- attention pooling + classifier
    k_gstats<<<BB, 256, 0, stream>>>(sarr, batch, wn, pooled);
    k_poolacc<<<(N_NODES + PC - 1) / PC, 256, 0, stream>>>(P, GS, wn, batch, pooled);
    {
        dim3 g((CC + BN - 1) / BN, (BB + BM - 1) / BM);
        k_gemm_nt<<<g, 256, 0, stream>>>(pooled, lin_w, out, BB, CC, DD, lin_b, 1);
    }
}